// Round 11
// baseline (352.546 us; speedup 1.0000x reference)
//
#include <hip/hip_runtime.h>
#include <stdint.h>

// ---------------- types / helpers ----------------
typedef __attribute__((ext_vector_type(4))) float f32x4;
typedef __attribute__((ext_vector_type(16))) float f32x16;
typedef __attribute__((ext_vector_type(8))) short short8;
typedef __attribute__((ext_vector_type(4))) short short4v;
typedef __attribute__((ext_vector_type(4))) unsigned uint4v;

__device__ __forceinline__ short f2bf(float f) {
  union { float f; uint32_t u; } v; v.f = f;
  uint32_t r = v.u + 0x7FFFu + ((v.u >> 16) & 1u);
  return (short)(r >> 16);
}

__device__ __forceinline__ unsigned cvt_pk_bf16(float lo, float hi) {
  unsigned r;
  asm("v_cvt_pk_bf16_f32 %0, %1, %2" : "=v"(r) : "v"(lo), "v"(hi));
  return r;
}

__device__ __forceinline__ f32x4 mfma16(short8 a, short8 b, f32x4 c) {
  return __builtin_amdgcn_mfma_f32_16x16x32_bf16(a, b, c, 0, 0, 0);
}
__device__ __forceinline__ f32x16 mfma32(short8 a, short8 b, f32x16 c) {
  return __builtin_amdgcn_mfma_f32_32x32x16_bf16(a, b, c, 0, 0, 0);
}

#define NB 8
#define LQ 2048
#define LKV 4096
#define DQ 256
#define FF 1024
#define NCHUNK 2
#define ROWS (NB * LQ)   // 16384

#define AS1(p) ((const __attribute__((address_space(1))) void*)(p))
#define AS3(p) ((__attribute__((address_space(3))) void*)(p))

// ---------------- all weight transposes in ONE launch ----------------
// out[C][R] = in[R][C], bf16 cast. Grid 704: Wk 64 | Wv 64 | Wo 64 | W1 256 | W2 256.
__global__ void transpose_all(
    const float* __restrict__ Wk, const float* __restrict__ Wv,
    const float* __restrict__ Wo, const float* __restrict__ W1,
    const float* __restrict__ W2,
    short* __restrict__ WkT, short* __restrict__ WvT, short* __restrict__ WoT,
    short* __restrict__ W1T, short* __restrict__ W2T) {
  __shared__ float t[32][33];
  int bid = blockIdx.x;
  const float* in; short* out; int R, C, b0;
  if (bid < 64)       { in = Wk; out = WkT; R = 256;  C = 256;  b0 = bid; }
  else if (bid < 128) { in = Wv; out = WvT; R = 256;  C = 256;  b0 = bid - 64; }
  else if (bid < 192) { in = Wo; out = WoT; R = 256;  C = 256;  b0 = bid - 128; }
  else if (bid < 448) { in = W1; out = W1T; R = 256;  C = 1024; b0 = bid - 192; }
  else                { in = W2; out = W2T; R = 1024; C = 256;  b0 = bid - 448; }
  int nbx = C / 32;
  int c0 = (b0 % nbx) * 32, r0 = (b0 / nbx) * 32;
  int tx = threadIdx.x, ty = threadIdx.y;  // 32 x 8
#pragma unroll
  for (int dy = 0; dy < 32; dy += 8)
    t[ty + dy][tx] = in[(long)(r0 + ty + dy) * C + c0 + tx];
  __syncthreads();
#pragma unroll
  for (int dy = 0; dy < 32; dy += 8)
    out[(long)(c0 + ty + dy) * R + r0 + tx] = f2bf(t[tx][ty + dy]);
}

// ---------------- generic GEMM: C[M,N] = A[M,K] * B[N,K]^T (+epilogues) ----------------
// Tile 128x128, BK=64, 4 waves. LDS layout [128][64] bf16, chunk swizzle c ^= (r&7).
// AMODE/BMODE: 0 = bf16 via global_load_lds; 1 = f32 reg-staged + cvt_pk; 2 = combine
// two Opart f32 planes with per-row softmax weights (A only).
// EPI: 0 = bf16 + bias[col]; 1 = bf16 + bias[row]; 2 = f32 + bias[col] + resid; 3 = relu bf16 + bias[col]
template <int AMODE, int BMODE, int EPI>
__global__ void __launch_bounds__(256, 2) gemm128(
    const void* __restrict__ A, long sAb, int lda,
    const void* __restrict__ B, long sBb, int ldb,
    const float* __restrict__ bias,
    const float* resid, long sRb,
    const float* __restrict__ Mcomb, const float* __restrict__ Lcomb,
    void* C, long sCb, int ldc, int K) {
  __shared__ char lds[32768];
  const int tid = threadIdx.x;
  const int bn = blockIdx.x, bm = blockIdx.y, bz = blockIdx.z;
  const int w = tid >> 6, l = tid & 63;
  const int wm = w & 1, wn = w >> 1;
  const int lr = l & 15, lq = l >> 4;

  auto stageReg = [&](const float* src, int ld, long row0, int k0, char* ldsb) {
#pragma unroll
    for (int it = 0; it < 4; ++it) {
      int idx = it * 2048 + tid * 8;
      int r = idx >> 6, c = idx & 63;
      const float* p = src + (row0 + r) * (long)ld + k0 + c;
      f32x4 f0 = *(const f32x4*)p, f1 = *(const f32x4*)(p + 4);
      uint4v u;
      u[0] = cvt_pk_bf16(f0[0], f0[1]); u[1] = cvt_pk_bf16(f0[2], f0[3]);
      u[2] = cvt_pk_bf16(f1[0], f1[1]); u[3] = cvt_pk_bf16(f1[2], f1[3]);
      *(short8*)(ldsb + ((r * 128 + c * 2) ^ ((r & 7) << 4))) = *(short8*)&u;
    }
  };
  auto stageGld = [&](const short* src, int ld, long row0, int k0, char* ldsb) {
#pragma unroll
    for (int it = 0; it < 4; ++it) {
      const int span = it * 4096 + w * 1024;     // wave-uniform
      int idx = (span >> 4) + l;                 // chunk index
      int r = idx >> 3, c = idx & 7;
      __builtin_amdgcn_global_load_lds(
          AS1(src + (row0 + r) * (long)ld + k0 + ((c ^ (r & 7)) * 8)),
          AS3(ldsb + span), 16, 0, 0);
    }
  };
  auto stageComb = [&](const float* O0, long row0, int k0, char* ldsb) {
#pragma unroll
    for (int it = 0; it < 4; ++it) {
      int idx = it * 2048 + tid * 8;
      int r = idx >> 6, c = idx & 63;
      long row = row0 + r;
      float m0 = Mcomb[row], m1 = Mcomb[ROWS + row];
      float l0 = Lcomb[row], l1 = Lcomb[ROWS + row];
      float M = fmaxf(m0, m1);
      float e0 = exp2f(m0 - M), e1 = exp2f(m1 - M);
      float inv = 1.f / (e0 * l0 + e1 * l1);
      float w0 = e0 * inv, w1 = e1 * inv;
      const float* p0 = O0 + row * 256 + k0 + c;
      const float* p1 = p0 + (long)ROWS * 256;
      f32x4 a0 = *(const f32x4*)p0, a1 = *(const f32x4*)(p0 + 4);
      f32x4 b0 = *(const f32x4*)p1, b1 = *(const f32x4*)(p1 + 4);
      uint4v u;
      u[0] = cvt_pk_bf16(w0 * a0[0] + w1 * b0[0], w0 * a0[1] + w1 * b0[1]);
      u[1] = cvt_pk_bf16(w0 * a0[2] + w1 * b0[2], w0 * a0[3] + w1 * b0[3]);
      u[2] = cvt_pk_bf16(w0 * a1[0] + w1 * b1[0], w0 * a1[1] + w1 * b1[1]);
      u[3] = cvt_pk_bf16(w0 * a1[2] + w1 * b1[2], w0 * a1[3] + w1 * b1[3]);
      *(short8*)(ldsb + ((r * 128 + c * 2) ^ ((r & 7) << 4))) = *(short8*)&u;
    }
  };

  f32x4 acc[4][4] = {};
  for (int k0 = 0; k0 < K; k0 += 64) {
    if (AMODE == 0)      stageGld((const short*)A + sAb * bz, lda, (long)bm * 128, k0, lds);
    else if (AMODE == 1) stageReg((const float*)A + sAb * bz, lda, (long)bm * 128, k0, lds);
    else                 stageComb((const float*)A, (long)bm * 128, k0, lds);
    if (BMODE == 0)      stageGld((const short*)B + sBb * bz, ldb, (long)bn * 128, k0, lds + 16384);
    else                 stageReg((const float*)B + sBb * bz, ldb, (long)bn * 128, k0, lds + 16384);
    __syncthreads();
    short8 af[4][2], bfr[4][2];
#pragma unroll
    for (int i = 0; i < 4; ++i) {
#pragma unroll
      for (int kk = 0; kk < 2; ++kk) {
        int ra = wm * 64 + i * 16 + lr;
        af[i][kk] = *(const short8*)(lds + ((ra * 128 + (kk * 32 + lq * 8) * 2) ^ ((ra & 7) << 4)));
        int rb = wn * 64 + i * 16 + lr;
        bfr[i][kk] = *(const short8*)(lds + 16384 + ((rb * 128 + (kk * 32 + lq * 8) * 2) ^ ((rb & 7) << 4)));
      }
    }
#pragma unroll
    for (int i = 0; i < 4; ++i)
#pragma unroll
      for (int j = 0; j < 4; ++j) {
        acc[i][j] = mfma16(af[i][0], bfr[j][0], acc[i][j]);
        acc[i][j] = mfma16(af[i][1], bfr[j][1], acc[i][j]);
      }
    __syncthreads();
  }
#pragma unroll
  for (int i = 0; i < 4; ++i) {
#pragma unroll
    for (int j = 0; j < 4; ++j) {
#pragma unroll
      for (int r = 0; r < 4; ++r) {
        long row = (long)bm * 128 + wm * 64 + i * 16 + lq * 4 + r;
        long col = (long)bn * 128 + wn * 64 + j * 16 + lr;
        float v = acc[i][j][r];
        if (EPI == 0) {
          v += bias[col];
          ((short*)C + sCb * bz)[row * ldc + col] = f2bf(v);
        } else if (EPI == 1) {
          v += bias[row];
          ((short*)C + sCb * bz)[row * ldc + col] = f2bf(v);
        } else if (EPI == 2) {
          v += bias[col] + (resid + sRb * bz)[row * ldc + col];
          ((float*)C + sCb * bz)[row * ldc + col] = v;
        } else {
          v += bias[col];
          v = fmaxf(v, 0.f);
          ((short*)C + sCb * bz)[row * ldc + col] = f2bf(v);
        }
      }
    }
  }
}

// ---------------- flash attention: 32q x 128d waves -> 2 waves/SIMD ----------------
// grid 512 (2 blocks/CU), n&7 = batch = XCD slot. Block 256 = 4 waves = (qh, dh):
// wave owns 32 q rows x 128 d-half; QK^T + softmax duplicated across the two d-waves
// (o[] halved to 4 x f32x16 = 64 regs -> ~220 unified regs/wave -> 2 waves/SIMD fit;
// R8's identical plan failed only because 240+AGPR blocked co-residency).
// LDS: single 64KB buffer (K 32KB + V^T 32KB); 2 blocks/CU = 128KB. Stage drain is
// covered by the other block's compute (cross-block TLP replaces dbuf).
__global__ void __launch_bounds__(256, 1) flash_attn(
    const float* __restrict__ Q, const short* __restrict__ Kb,
    const short* __restrict__ Vt, float* __restrict__ Opart,
    float* __restrict__ Mb, float* __restrict__ Lb) {
  __shared__ char lds[65536];
  char* kq = lds;          // K tile [64 kv][256 d], swz ^((r&15)<<4) on 16B chunks
  char* vt = lds + 32768;  // V^T tile [256 d][64 kv], swz ^((d&7)<<4)
  const int tid = threadIdx.x;
  const int n = blockIdx.x;
  const int b = n & 7;           // XCD-local batch
  const int slot = n >> 3;       // [0,64)
  const int qt = slot & 31;      // 32 q-tiles of 64 rows
  const int ch = slot >> 5;      // [0,2)
  const int wid = tid >> 6, l = tid & 63;
  const int ql = l & 31, h = l >> 5;
  const int qh = wid & 1, dh = wid >> 1;
  const int qrow0 = qt * 64 + qh * 32;
  const float* Qp = Q + ((long)b * LQ + qrow0 + ql) * DQ;
  const short* Kp = Kb + (long)b * LKV * DQ;
  const short* Vp = Vt + (long)b * DQ * LKV;
  const float SCQ = 0.0625f * 1.4426950408889634f;  // folded into Q cast

  // async stage tile via global_load_lds: linear LDS dest, inverse-swizzled source.
  auto stage = [&](int kv0) {
#pragma unroll
    for (int i = 0; i < 8; ++i) {
      const int j = wid * 8192 + i * 1024;       // wave-uniform LDS span base
      {
        int r = (j >> 9) + (l >> 5);
        int cc = l & 31;
        const short* gk = Kp + (long)(kv0 + r) * DQ + ((cc ^ (r & 15)) * 8);
        __builtin_amdgcn_global_load_lds(AS1(gk), AS3(kq + j), 16, 0, 0);
      }
      {
        int d = (j >> 7) + (l >> 3);
        int cc = l & 7;
        const short* gv = Vp + (long)d * LKV + kv0 + ((cc ^ (d & 7)) * 8);
        __builtin_amdgcn_global_load_lds(AS1(gv), AS3(vt + j), 16, 0, 0);
      }
    }
  };

  // preload Q fragments (pre-scaled): lane l supplies Q[q=ql][c=16w+8h+j]
  short8 qf[16];
#pragma unroll
  for (int w = 0; w < 16; ++w) {
    const float* p = Qp + w * 16 + h * 8;
    f32x4 f0 = *(const f32x4*)p, f1 = *(const f32x4*)(p + 4);
    short8 v;
#pragma unroll
    for (int j = 0; j < 4; ++j) { v[j] = f2bf(f0[j] * SCQ); v[4 + j] = f2bf(f1[j] * SCQ); }
    qf[w] = v;
  }

  f32x16 o[4] = {};          // O[32q x 128d-half] accumulator (4 d-tiles of 32)
  float m_r = -1e30f, l_r = 0.f;

  const int kv_lo = ch * (LKV / NCHUNK);
  const int NT = (LKV / NCHUNK) / 64;   // 32 tiles

  for (int t = 0; t < NT; ++t) {
    stage(kv_lo + t * 64);
    asm volatile("s_waitcnt vmcnt(0)" ::: "memory");
    __builtin_amdgcn_s_barrier();
    __builtin_amdgcn_sched_barrier(0);

    // ---- QK^T both 32-kv subtiles: two independent MFMA chains, interleaved ----
    f32x16 sa = {}, sb = {};
    {
      const int krA = ql, krB = 32 + ql;
      const int baseA = krA * 512, swzA = (krA & 15) << 4;
      const int baseB = krB * 512, swzB = (krB & 15) << 4;
#pragma unroll
      for (int w = 0; w < 16; ++w) {
        short8 kfA = *(const short8*)(kq + ((baseA + w * 32 + h * 16) ^ swzA));
        sa = mfma32(kfA, qf[w], sa);
        short8 kfB = *(const short8*)(kq + ((baseB + w * 32 + h * 16) ^ swzB));
        sb = mfma32(kfB, qf[w], sb);
      }
    }

    // ---- tree-max (depth 5) + single deferred rescale ----
    {
      float m8[8];
#pragma unroll
      for (int i = 0; i < 8; ++i)
        m8[i] = fmaxf(fmaxf(sa[i], sa[i + 8]), fmaxf(sb[i], sb[i + 8]));
      float m0 = fmaxf(fmaxf(m8[0], m8[1]), fmaxf(m8[2], m8[3]));
      float m1 = fmaxf(fmaxf(m8[4], m8[5]), fmaxf(m8[6], m8[7]));
      float pmax = fmaxf(m0, m1);
      pmax = fmaxf(pmax, __shfl_xor(pmax, 32));
      if (__any(pmax > m_r + 8.f)) {
        float mn = fmaxf(m_r, pmax);
        float alpha = exp2f(m_r - mn);
        m_r = mn;
        l_r *= alpha;
#pragma unroll
        for (int rr = 0; rr < 16; ++rr) {
          int src = ((rr & 3) + 8 * (rr >> 2) + 4 * h) + 32 * h;
          float ar = __shfl(alpha, src);
#pragma unroll
          for (int nn = 0; nn < 4; ++nn) o[nn][rr] *= ar;
        }
      }
    }

    // ---- exp2 + pack both subtiles (4 partial sums), row-sum ----
    unsigned wpkA[8], wpkB[8];
    {
      float rs0 = 0.f, rs1 = 0.f, rs2 = 0.f, rs3 = 0.f;
#pragma unroll
      for (int k = 0; k < 8; ++k) {
        float a0 = exp2f(sa[2 * k] - m_r);
        float a1 = exp2f(sa[2 * k + 1] - m_r);
        float b0 = exp2f(sb[2 * k] - m_r);
        float b1 = exp2f(sb[2 * k + 1] - m_r);
        rs0 += a0; rs1 += a1; rs2 += b0; rs3 += b1;
        wpkA[k] = cvt_pk_bf16(a0, a1);
        wpkB[k] = cvt_pk_bf16(b0, b1);
      }
      float rs = (rs0 + rs1) + (rs2 + rs3);
      rs += __shfl_xor(rs, 32);
      l_r += rs;
    }
    // exchange with lane^32 -> PV A-frags: A[m=q][k=16v+8h+j]
    short8 paA[2], paB[2];
#pragma unroll
    for (int v = 0; v < 2; ++v) {
      {
        unsigned a0 = wpkA[4 * v], a1 = wpkA[4 * v + 1];
        unsigned b0 = wpkA[4 * v + 2], b1 = wpkA[4 * v + 3];
        unsigned own0 = h ? b0 : a0, own1 = h ? b1 : a1;
        unsigned snd0 = h ? a0 : b0, snd1 = h ? a1 : b1;
        unsigned rcv0 = __shfl_xor((int)snd0, 32), rcv1 = __shfl_xor((int)snd1, 32);
        unsigned lo0 = h ? rcv0 : own0, lo1 = h ? rcv1 : own1;
        unsigned hi0 = h ? own0 : rcv0, hi1 = h ? own1 : rcv1;
        uint4v u = {lo0, lo1, hi0, hi1};
        paA[v] = *(short8*)&u;
      }
      {
        unsigned a0 = wpkB[4 * v], a1 = wpkB[4 * v + 1];
        unsigned b0 = wpkB[4 * v + 2], b1 = wpkB[4 * v + 3];
        unsigned own0 = h ? b0 : a0, own1 = h ? b1 : a1;
        unsigned snd0 = h ? a0 : b0, snd1 = h ? a1 : b1;
        unsigned rcv0 = __shfl_xor((int)snd0, 32), rcv1 = __shfl_xor((int)snd1, 32);
        unsigned lo0 = h ? rcv0 : own0, lo1 = h ? rcv1 : own1;
        unsigned hi0 = h ? own0 : rcv0, hi1 = h ? own1 : rcv1;
        uint4v u = {lo0, lo1, hi0, hi1};
        paB[v] = *(short8*)&u;
      }
    }

    // ---- O += P V' on this wave's 128-d half: 4 o-chains x 4 mfma ----
#pragma unroll
    for (int nn = 0; nn < 4; ++nn) {
      const int d = 128 * dh + 32 * nn + ql;
      const int dbase = d * 128, dswz = (d & 7) << 4;
      short8 bv0 = *(const short8*)(vt + ((dbase + 0 * 32 + 16 * h) ^ dswz));
      o[nn] = mfma32(paA[0], bv0, o[nn]);
      short8 bv1 = *(const short8*)(vt + ((dbase + 1 * 32 + 16 * h) ^ dswz));
      o[nn] = mfma32(paA[1], bv1, o[nn]);
      short8 bv2 = *(const short8*)(vt + ((dbase + 2 * 32 + 16 * h) ^ dswz));
      o[nn] = mfma32(paB[0], bv2, o[nn]);
      short8 bv3 = *(const short8*)(vt + ((dbase + 3 * 32 + 16 * h) ^ dswz));
      o[nn] = mfma32(paB[1], bv3, o[nn]);
    }

    asm volatile("s_waitcnt lgkmcnt(0)" ::: "memory");  // all LDS reads consumed
    __builtin_amdgcn_s_barrier();                        // buf safe to overwrite next iter
    __builtin_amdgcn_sched_barrier(0);
  }

  // epilogue: unnormalized partial O (f32) + per-row m,l
  const long rowb = (long)b * LQ + qrow0;
#pragma unroll
  for (int rr = 0; rr < 16; ++rr) {
    long grow = rowb + (rr & 3) + 8 * (rr >> 2) + 4 * h;
    float* dst = Opart + ((long)ch * ROWS + grow) * 256 + 128 * dh + ql;
#pragma unroll
    for (int nn = 0; nn < 4; ++nn) dst[32 * nn] = o[nn][rr];
  }
  if (dh == 0 && h == 0) {
    Mb[(long)ch * ROWS + rowb + ql] = m_r;
    Lb[(long)ch * ROWS + rowb + ql] = l_r;
  }
}

// ---------------- layernorm over rows of 256 ----------------
__global__ void __launch_bounds__(256) ln256(
    const float* in, float* outF, short* outB,
    const float* __restrict__ g, const float* __restrict__ be) {
  const int w = threadIdx.x >> 6, l = threadIdx.x & 63;
  const long row = (long)blockIdx.x * 4 + w;
  const float* p = in + row * 256 + l * 4;
  f32x4 x = *(const f32x4*)p;
  float s = x[0] + x[1] + x[2] + x[3];
  float s2 = x[0] * x[0] + x[1] * x[1] + x[2] * x[2] + x[3] * x[3];
#pragma unroll
  for (int mk = 1; mk < 64; mk <<= 1) { s += __shfl_xor(s, mk); s2 += __shfl_xor(s2, mk); }
  float mu = s * (1.f / 256.f);
  float var = s2 * (1.f / 256.f) - mu * mu;
  float rstd = rsqrtf(var + 1e-5f);
  f32x4 gg = *(const f32x4*)(g + l * 4);
  f32x4 bb = *(const f32x4*)(be + l * 4);
  f32x4 y;
#pragma unroll
  for (int k = 0; k < 4; ++k) y[k] = (x[k] - mu) * rstd * gg[k] + bb[k];
  if (outF) *(f32x4*)(outF + row * 256 + l * 4) = y;
  if (outB) {
    short4v yb;
#pragma unroll
    for (int k = 0; k < 4; ++k) yb[k] = f2bf(y[k]);
    *(short4v*)(outB + row * 256 + l * 4) = yb;
  }
}

// ---------------- launcher ----------------
extern "C" void kernel_launch(void* const* d_in, const int* in_sizes, int n_in,
                              void* d_out, int out_size, void* d_ws, size_t ws_size,
                              hipStream_t stream) {
  const float* query = (const float*)d_in[0];
  const float* key   = (const float*)d_in[1];
  const float* value = (const float*)d_in[2];
  const float* Wk  = (const float*)d_in[3];
  const float* bk  = (const float*)d_in[4];
  const float* Wv  = (const float*)d_in[5];
  const float* bv  = (const float*)d_in[6];
  const float* Wo  = (const float*)d_in[7];
  const float* bo  = (const float*)d_in[8];
  const float* g1  = (const float*)d_in[9];
  const float* b1  = (const float*)d_in[10];
  const float* g2  = (const float*)d_in[11];
  const float* b2  = (const float*)d_in[12];
  const float* W1  = (const float*)d_in[13];
  const float* bf1 = (const float*)d_in[14];
  const float* W2  = (const float*)d_in[15];
  const float* bf2 = (const float*)d_in[16];

  char* ws = (char*)d_ws;
  size_t off = 0;
  auto take = [&](size_t bytes) { char* p = ws + off; off += bytes; return p; };
  short* WkT = (short*)take((size_t)256 * 256 * 2);
  short* WvT = (short*)take((size_t)256 * 256 * 2);
  short* WoT = (short*)take((size_t)256 * 256 * 2);
  short* W1T = (short*)take((size_t)1024 * 256 * 2);
  short* W2T = (short*)take((size_t)256 * 1024 * 2);
  short* Kb  = (short*)take((size_t)NB * LKV * DQ * 2);   // dead after flash -> Hb aliases
  short* Vt  = (short*)take((size_t)NB * DQ * LKV * 2);
  float* Opart = (float*)take((size_t)NCHUNK * ROWS * 256 * 4);  // dead after Wo -> Xb aliases
  float* Mbuf  = (float*)take((size_t)NCHUNK * ROWS * 4);
  float* Lbuf  = (float*)take((size_t)NCHUNK * ROWS * 4);
  float* Xf    = (float*)take((size_t)ROWS * 256 * 4);
  short* Xb  = (short*)Opart;            // LN1 bf16 out (Opart dead)
  short* Hb  = (short*)Kb;               // FF1 out 33.6MB = Kb+Vt region (dead)
  (void)ws_size; (void)in_sizes; (void)n_in; (void)out_size;

  dim3 blk(256);
  transpose_all<<<dim3(704), dim3(32, 8), 0, stream>>>(
      Wk, Wv, Wo, W1, W2, WkT, WvT, WoT, W1T, W2T);

  // K' = key @ Wk + bk   -> Kb [B*LKV][256] bf16   (A: f32 reg, B: bf16 gload)
  gemm128<1, 0, 0><<<dim3(2, 256, 1), blk, 0, stream>>>(
      key, 0, 256, WkT, 0, 256, bk, nullptr, 0, nullptr, nullptr, Kb, 0, 256, 256);
  // V'^T = (value @ Wv + bv)^T -> Vt [B][256][LKV] bf16  (A = WvT gload, B = value f32)
  gemm128<0, 1, 1><<<dim3(32, 2, 8), blk, 0, stream>>>(
      WvT, 0, 256, value, (long)LKV * 256, 256, bv, nullptr, 0, nullptr, nullptr,
      Vt, (long)256 * LKV, LKV, 256);
  // attention (KV-split 2, 32qx128d waves, 2 blocks/CU, XCD-pinned)
  flash_attn<<<dim3(512), blk, 0, stream>>>(query, Kb, Vt, Opart, Mbuf, Lbuf);
  // attn_out = combine(Opart) @ Wo + bo + query -> Xf f32   (combine fused in A-stage)
  gemm128<2, 0, 2><<<dim3(2, 128, 1), blk, 0, stream>>>(
      Opart, 0, 256, WoT, 0, 256, bo, query, 0, Mbuf, Lbuf, Xf, 0, 256, 256);
  // x = LN1(Xf) -> Xf (f32, in-place) + Xb (bf16)
  ln256<<<4096, blk, 0, stream>>>(Xf, Xf, Xb, g1, b1);
  // h = relu(x @ W1 + bf1) -> Hb bf16  (both operands gload)
  gemm128<0, 0, 3><<<dim3(8, 128, 1), blk, 0, stream>>>(
      Xb, 0, 256, W1T, 0, 256, bf1, nullptr, 0, nullptr, nullptr, Hb, 0, 1024, 256);
  // y = h @ W2 + bf2 + x -> Xf (in-place)
  gemm128<0, 0, 2><<<dim3(2, 128, 1), blk, 0, stream>>>(
      Hb, 0, 1024, W2T, 0, 1024, bf2, Xf, 0, nullptr, nullptr, Xf, 0, 256, 1024);
  // out = LN2(Xf)
  ln256<<<4096, blk, 0, stream>>>(Xf, (float*)d_out, nullptr, g2, b2);
}

// Round 12
// 227.253 us; speedup vs baseline: 1.5513x; 1.5513x over previous
//
#include <hip/hip_runtime.h>
#include <stdint.h>

// ---------------- types / helpers ----------------
typedef __attribute__((ext_vector_type(4))) float f32x4;
typedef __attribute__((ext_vector_type(16))) float f32x16;
typedef __attribute__((ext_vector_type(8))) short short8;
typedef __attribute__((ext_vector_type(4))) short short4v;
typedef __attribute__((ext_vector_type(4))) unsigned uint4v;

__device__ __forceinline__ short f2bf(float f) {
  union { float f; uint32_t u; } v; v.f = f;
  uint32_t r = v.u + 0x7FFFu + ((v.u >> 16) & 1u);
  return (short)(r >> 16);
}

__device__ __forceinline__ unsigned cvt_pk_bf16(float lo, float hi) {
  unsigned r;
  asm("v_cvt_pk_bf16_f32 %0, %1, %2" : "=v"(r) : "v"(lo), "v"(hi));
  return r;
}

__device__ __forceinline__ f32x4 mfma16(short8 a, short8 b, f32x4 c) {
  return __builtin_amdgcn_mfma_f32_16x16x32_bf16(a, b, c, 0, 0, 0);
}
__device__ __forceinline__ f32x16 mfma32(short8 a, short8 b, f32x16 c) {
  return __builtin_amdgcn_mfma_f32_32x32x16_bf16(a, b, c, 0, 0, 0);
}

#define NB 8
#define LQ 2048
#define LKV 4096
#define DQ 256
#define FF 1024
#define NCHUNK 2
#define ROWS (NB * LQ)   // 16384

#define AS1(p) ((const __attribute__((address_space(1))) void*)(p))
#define AS3(p) ((__attribute__((address_space(3))) void*)(p))

// ---------------- all weight transposes in ONE launch ----------------
__global__ void transpose_all(
    const float* __restrict__ Wk, const float* __restrict__ Wv,
    const float* __restrict__ Wo, const float* __restrict__ W1,
    const float* __restrict__ W2,
    short* __restrict__ WkT, short* __restrict__ WvT, short* __restrict__ WoT,
    short* __restrict__ W1T, short* __restrict__ W2T) {
  __shared__ float t[32][33];
  int bid = blockIdx.x;
  const float* in; short* out; int R, C, b0;
  if (bid < 64)       { in = Wk; out = WkT; R = 256;  C = 256;  b0 = bid; }
  else if (bid < 128) { in = Wv; out = WvT; R = 256;  C = 256;  b0 = bid - 64; }
  else if (bid < 192) { in = Wo; out = WoT; R = 256;  C = 256;  b0 = bid - 128; }
  else if (bid < 448) { in = W1; out = W1T; R = 256;  C = 1024; b0 = bid - 192; }
  else                { in = W2; out = W2T; R = 1024; C = 256;  b0 = bid - 448; }
  int nbx = C / 32;
  int c0 = (b0 % nbx) * 32, r0 = (b0 / nbx) * 32;
  int tx = threadIdx.x, ty = threadIdx.y;  // 32 x 8
#pragma unroll
  for (int dy = 0; dy < 32; dy += 8)
    t[ty + dy][tx] = in[(long)(r0 + ty + dy) * C + c0 + tx];
  __syncthreads();
#pragma unroll
  for (int dy = 0; dy < 32; dy += 8)
    out[(long)(c0 + ty + dy) * R + r0 + tx] = f2bf(t[tx][ty + dy]);
}

// ---------------- generic GEMM: C[M,N] = A[M,K] * B[N,K]^T (+epilogues) ----------------
// Tile 128x128, BK=64, 4 waves. AMODE/BMODE: 0 = bf16 via global_load_lds; 1 = f32 reg+cvt_pk.
// EPI: 0 = bf16 + bias[col]; 1 = bf16 + bias[row]; 3 = relu bf16 + bias[col]
template <int AMODE, int BMODE, int EPI>
__global__ void __launch_bounds__(256, 2) gemm128(
    const void* __restrict__ A, long sAb, int lda,
    const void* __restrict__ B, long sBb, int ldb,
    const float* __restrict__ bias,
    void* C, long sCb, int ldc, int K) {
  __shared__ char lds[32768];
  const int tid = threadIdx.x;
  const int bn = blockIdx.x, bm = blockIdx.y, bz = blockIdx.z;
  const int w = tid >> 6, l = tid & 63;
  const int wm = w & 1, wn = w >> 1;
  const int lr = l & 15, lq = l >> 4;

  auto stageReg = [&](const float* src, int ld, long row0, int k0, char* ldsb) {
#pragma unroll
    for (int it = 0; it < 4; ++it) {
      int idx = it * 2048 + tid * 8;
      int r = idx >> 6, c = idx & 63;
      const float* p = src + (row0 + r) * (long)ld + k0 + c;
      f32x4 f0 = *(const f32x4*)p, f1 = *(const f32x4*)(p + 4);
      uint4v u;
      u[0] = cvt_pk_bf16(f0[0], f0[1]); u[1] = cvt_pk_bf16(f0[2], f0[3]);
      u[2] = cvt_pk_bf16(f1[0], f1[1]); u[3] = cvt_pk_bf16(f1[2], f1[3]);
      *(short8*)(ldsb + ((r * 128 + c * 2) ^ ((r & 7) << 4))) = *(short8*)&u;
    }
  };
  auto stageGld = [&](const short* src, int ld, long row0, int k0, char* ldsb) {
#pragma unroll
    for (int it = 0; it < 4; ++it) {
      const int span = it * 4096 + w * 1024;     // wave-uniform
      int idx = (span >> 4) + l;                 // chunk index
      int r = idx >> 3, c = idx & 7;
      __builtin_amdgcn_global_load_lds(
          AS1(src + (row0 + r) * (long)ld + k0 + ((c ^ (r & 7)) * 8)),
          AS3(ldsb + span), 16, 0, 0);
    }
  };

  f32x4 acc[4][4] = {};
  for (int k0 = 0; k0 < K; k0 += 64) {
    if (AMODE == 0)      stageGld((const short*)A + sAb * bz, lda, (long)bm * 128, k0, lds);
    else                 stageReg((const float*)A + sAb * bz, lda, (long)bm * 128, k0, lds);
    if (BMODE == 0)      stageGld((const short*)B + sBb * bz, ldb, (long)bn * 128, k0, lds + 16384);
    else                 stageReg((const float*)B + sBb * bz, ldb, (long)bn * 128, k0, lds + 16384);
    __syncthreads();
    short8 af[4][2], bfr[4][2];
#pragma unroll
    for (int i = 0; i < 4; ++i) {
#pragma unroll
      for (int kk = 0; kk < 2; ++kk) {
        int ra = wm * 64 + i * 16 + lr;
        af[i][kk] = *(const short8*)(lds + ((ra * 128 + (kk * 32 + lq * 8) * 2) ^ ((ra & 7) << 4)));
        int rb = wn * 64 + i * 16 + lr;
        bfr[i][kk] = *(const short8*)(lds + 16384 + ((rb * 128 + (kk * 32 + lq * 8) * 2) ^ ((rb & 7) << 4)));
      }
    }
#pragma unroll
    for (int i = 0; i < 4; ++i)
#pragma unroll
      for (int j = 0; j < 4; ++j) {
        acc[i][j] = mfma16(af[i][0], bfr[j][0], acc[i][j]);
        acc[i][j] = mfma16(af[i][1], bfr[j][1], acc[i][j]);
      }
    __syncthreads();
  }
#pragma unroll
  for (int i = 0; i < 4; ++i) {
#pragma unroll
    for (int j = 0; j < 4; ++j) {
#pragma unroll
      for (int r = 0; r < 4; ++r) {
        long row = (long)bm * 128 + wm * 64 + i * 16 + lq * 4 + r;
        long col = (long)bn * 128 + wn * 64 + j * 16 + lr;
        float v = acc[i][j][r];
        if (EPI == 0) {
          v += bias[col];
          ((short*)C + sCb * bz)[row * ldc + col] = f2bf(v);
        } else if (EPI == 1) {
          v += bias[row];
          ((short*)C + sCb * bz)[row * ldc + col] = f2bf(v);
        } else {
          v += bias[col];
          v = fmaxf(v, 0.f);
          ((short*)C + sCb * bz)[row * ldc + col] = f2bf(v);
        }
      }
    }
  }
}

// ---------------- GEMM + fused LayerNorm: C[M,256] = A[M,K] * B[256,K]^T ----------------
// Tile 64 rows x 256 cols (FULL width -> LN per row stays in-block). 4 waves x 16 rows.
// AMODE: 0 = bf16 A via global_load_lds; 2 = combine two Opart f32 planes (softmax merge).
// Epilogue: v = acc + bias[col] + resid[row][col]; y = LN(v)*g+be; write outF (f32)
// and optionally outB (bf16). LN reduce: 16 in-lane adds + shfl_xor(1,2,4,8) in lr-group.
template <int AMODE, bool WB16>
__global__ void __launch_bounds__(256, 2) gemmln(
    const void* __restrict__ A, const short* __restrict__ Bw,
    const float* __restrict__ bias, const float* __restrict__ resid,
    const float* __restrict__ Mcomb, const float* __restrict__ Lcomb,
    const float* __restrict__ g, const float* __restrict__ be,
    float* __restrict__ outF, short* __restrict__ outB, int K) {
  __shared__ char lds[40960];    // A 8KB @0, B 32KB @8192
  const int tid = threadIdx.x;
  const int bm = blockIdx.x;     // 256 blocks x 64 rows
  const int w = tid >> 6, l = tid & 63;
  const int lr = l & 15, lq = l >> 4;
  char* ldsA = lds;
  char* ldsB = lds + 8192;

  f32x4 acc[16] = {};
  for (int k0 = 0; k0 < K; k0 += 64) {
    // ---- stage A tile [64][64] ----
    if (AMODE == 0) {
      const short* src = (const short*)A;
#pragma unroll
      for (int it = 0; it < 2; ++it) {
        const int span = it * 4096 + w * 1024;
        int idx = (span >> 4) + l;
        int r = idx >> 3, c = idx & 7;
        __builtin_amdgcn_global_load_lds(
            AS1(src + ((long)bm * 64 + r) * K + k0 + ((c ^ (r & 7)) * 8)),
            AS3(ldsA + span), 16, 0, 0);
      }
    } else {
      const float* O0 = (const float*)A;
#pragma unroll
      for (int it = 0; it < 2; ++it) {
        int idx = it * 2048 + tid * 8;
        int r = idx >> 6, c = idx & 63;
        long row = (long)bm * 64 + r;
        float m0 = Mcomb[row], m1 = Mcomb[ROWS + row];
        float l0 = Lcomb[row], l1 = Lcomb[ROWS + row];
        float M = fmaxf(m0, m1);
        float e0 = exp2f(m0 - M), e1 = exp2f(m1 - M);
        float inv = 1.f / (e0 * l0 + e1 * l1);
        float w0 = e0 * inv, w1 = e1 * inv;
        const float* p0 = O0 + row * 256 + k0 + c;
        const float* p1 = p0 + (long)ROWS * 256;
        f32x4 a0 = *(const f32x4*)p0, a1 = *(const f32x4*)(p0 + 4);
        f32x4 b0 = *(const f32x4*)p1, b1 = *(const f32x4*)(p1 + 4);
        uint4v u;
        u[0] = cvt_pk_bf16(w0 * a0[0] + w1 * b0[0], w0 * a0[1] + w1 * b0[1]);
        u[1] = cvt_pk_bf16(w0 * a0[2] + w1 * b0[2], w0 * a0[3] + w1 * b0[3]);
        u[2] = cvt_pk_bf16(w0 * a1[0] + w1 * b1[0], w0 * a1[1] + w1 * b1[1]);
        u[3] = cvt_pk_bf16(w0 * a1[2] + w1 * b1[2], w0 * a1[3] + w1 * b1[3]);
        *(short8*)(ldsA + ((r * 128 + c * 2) ^ ((r & 7) << 4))) = *(short8*)&u;
      }
    }
    // ---- stage B tile [256][64] ----
#pragma unroll
    for (int it = 0; it < 8; ++it) {
      const int span = it * 4096 + w * 1024;
      int idx = (span >> 4) + l;
      int r = idx >> 3, c = idx & 7;
      __builtin_amdgcn_global_load_lds(
          AS1(Bw + (long)r * K + k0 + ((c ^ (r & 7)) * 8)),
          AS3(ldsB + span), 16, 0, 0);
    }
    __syncthreads();
    short8 af0, af1;
    {
      int ra = w * 16 + lr;
      af0 = *(const short8*)(ldsA + ((ra * 128 + (lq * 8) * 2) ^ ((ra & 7) << 4)));
      af1 = *(const short8*)(ldsA + ((ra * 128 + (32 + lq * 8) * 2) ^ ((ra & 7) << 4)));
    }
#pragma unroll
    for (int j = 0; j < 16; ++j) {
      int rb = j * 16 + lr;
      short8 b0 = *(const short8*)(ldsB + ((rb * 128 + (lq * 8) * 2) ^ ((rb & 7) << 4)));
      short8 b1 = *(const short8*)(ldsB + ((rb * 128 + (32 + lq * 8) * 2) ^ ((rb & 7) << 4)));
      acc[j] = mfma16(af0, b0, acc[j]);
      acc[j] = mfma16(af1, b1, acc[j]);
    }
    __syncthreads();
  }

  // ---- epilogue: bias + resid, LN over each row, write ----
  const long rowbase = (long)bm * 64 + w * 16;
  float bia[16], gg[16], bb[16];
#pragma unroll
  for (int j = 0; j < 16; ++j) {
    int col = j * 16 + lr;
    bia[j] = bias[col]; gg[j] = g[col]; bb[j] = be[col];
  }
#pragma unroll
  for (int r = 0; r < 4; ++r) {
    long row = rowbase + lq * 4 + r;
    float v[16];
    float s = 0.f, s2 = 0.f;
#pragma unroll
    for (int j = 0; j < 16; ++j) {
      float x = acc[j][r] + bia[j] + resid[row * 256 + j * 16 + lr];
      v[j] = x; s += x; s2 += x * x;
    }
#pragma unroll
    for (int mk = 1; mk < 16; mk <<= 1) { s += __shfl_xor(s, mk); s2 += __shfl_xor(s2, mk); }
    float mu = s * (1.f / 256.f);
    float var = s2 * (1.f / 256.f) - mu * mu;
    float rstd = rsqrtf(var + 1e-5f);
#pragma unroll
    for (int j = 0; j < 16; ++j) {
      int col = j * 16 + lr;
      float y = (v[j] - mu) * rstd * gg[j] + bb[j];
      outF[row * 256 + col] = y;
      if (WB16) outB[row * 256 + col] = f2bf(y);
    }
  }
}

// ---------------- flash attention: swapped-QK^T 32x32, batched subtiles, dbuf ----------------
// R10-proven (136us): grid 256 (1 block/CU), n&7 = batch = XCD slot (per-XCD KV = 4MB = L2).
// Block 256 = 4 waves, wave owns 32 q rows. LDS: 2 x (K 32KB + V^T 32KB) = 128KB,
// counted vmcnt(16). 1 wave/SIMD (register-locked; R8/R11 showed 2 w/SIMD unreachable
// with the 32qx256d accumulator) -> parallelism is pure ILP: both 32-kv subtiles'
// QK chains interleaved, one tree-max + single deferred rescale, PV 8x4-deep chains.
__global__ void __launch_bounds__(256, 1) flash_attn(
    const float* __restrict__ Q, const short* __restrict__ Kb,
    const short* __restrict__ Vt, float* __restrict__ Opart,
    float* __restrict__ Mb, float* __restrict__ Lb) {
  __shared__ char lds[131072];
  const int tid = threadIdx.x;
  const int n = blockIdx.x;
  const int b = n & 7;           // XCD-local batch
  const int slot = n >> 3;       // [0,32)
  const int qt = slot & 15;
  const int ch = slot >> 4;      // [0,2)
  const int wid = tid >> 6, l = tid & 63;
  const int ql = l & 31, h = l >> 5;
  const int qrow0 = qt * 128 + wid * 32;
  const float* Qp = Q + ((long)b * LQ + qrow0 + ql) * DQ;
  const short* Kp = Kb + (long)b * LKV * DQ;
  const short* Vp = Vt + (long)b * DQ * LKV;
  const float SCQ = 0.0625f * 1.4426950408889634f;  // folded into Q cast

  auto stage = [&](int bufb, int kv0) {
    char* kqb = lds + bufb * 65536;
    char* vtb = kqb + 32768;
#pragma unroll
    for (int i = 0; i < 8; ++i) {
      const int j = wid * 8192 + i * 1024;       // wave-uniform LDS span base
      {
        int r = (j >> 9) + (l >> 5);
        int cc = l & 31;
        const short* gk = Kp + (long)(kv0 + r) * DQ + ((cc ^ (r & 15)) * 8);
        __builtin_amdgcn_global_load_lds(AS1(gk), AS3(kqb + j), 16, 0, 0);
      }
      {
        int d = (j >> 7) + (l >> 3);
        int cc = l & 7;
        const short* gv = Vp + (long)d * LKV + kv0 + ((cc ^ (d & 7)) * 8);
        __builtin_amdgcn_global_load_lds(AS1(gv), AS3(vtb + j), 16, 0, 0);
      }
    }
  };

  short8 qf[16];
#pragma unroll
  for (int w = 0; w < 16; ++w) {
    const float* p = Qp + w * 16 + h * 8;
    f32x4 f0 = *(const f32x4*)p, f1 = *(const f32x4*)(p + 4);
    short8 v;
#pragma unroll
    for (int j = 0; j < 4; ++j) { v[j] = f2bf(f0[j] * SCQ); v[4 + j] = f2bf(f1[j] * SCQ); }
    qf[w] = v;
  }

  f32x16 o[8] = {};
  float m_r = -1e30f, l_r = 0.f;

  const int kv_lo = ch * (LKV / NCHUNK);
  const int NT = (LKV / NCHUNK) / 64;   // 32 tiles

  stage(0, kv_lo);

  for (int t = 0; t < NT; ++t) {
    if (t + 1 < NT) {
      stage((t + 1) & 1, kv_lo + (t + 1) * 64);
      asm volatile("s_waitcnt vmcnt(16)" ::: "memory");
    } else {
      asm volatile("s_waitcnt vmcnt(0)" ::: "memory");
    }
    __builtin_amdgcn_s_barrier();
    __builtin_amdgcn_sched_barrier(0);
    char* kq = lds + (t & 1) * 65536;
    char* vt = kq + 32768;

    f32x16 sa = {}, sb = {};
    {
      const int krA = ql, krB = 32 + ql;
      const int baseA = krA * 512, swzA = (krA & 15) << 4;
      const int baseB = krB * 512, swzB = (krB & 15) << 4;
#pragma unroll
      for (int w = 0; w < 16; ++w) {
        short8 kfA = *(const short8*)(kq + ((baseA + w * 32 + h * 16) ^ swzA));
        sa = mfma32(kfA, qf[w], sa);
        short8 kfB = *(const short8*)(kq + ((baseB + w * 32 + h * 16) ^ swzB));
        sb = mfma32(kfB, qf[w], sb);
      }
    }

    {
      float m8[8];
#pragma unroll
      for (int i = 0; i < 8; ++i)
        m8[i] = fmaxf(fmaxf(sa[i], sa[i + 8]), fmaxf(sb[i], sb[i + 8]));
      float m0 = fmaxf(fmaxf(m8[0], m8[1]), fmaxf(m8[2], m8[3]));
      float m1 = fmaxf(fmaxf(m8[4], m8[5]), fmaxf(m8[6], m8[7]));
      float pmax = fmaxf(m0, m1);
      pmax = fmaxf(pmax, __shfl_xor(pmax, 32));
      if (__any(pmax > m_r + 8.f)) {
        float mn = fmaxf(m_r, pmax);
        float alpha = exp2f(m_r - mn);
        m_r = mn;
        l_r *= alpha;
#pragma unroll
        for (int rr = 0; rr < 16; ++rr) {
          int src = ((rr & 3) + 8 * (rr >> 2) + 4 * h) + 32 * h;
          float ar = __shfl(alpha, src);
#pragma unroll
          for (int nn = 0; nn < 8; ++nn) o[nn][rr] *= ar;
        }
      }
    }

    unsigned wpkA[8], wpkB[8];
    {
      float rs0 = 0.f, rs1 = 0.f, rs2 = 0.f, rs3 = 0.f;
#pragma unroll
      for (int k = 0; k < 8; ++k) {
        float a0 = exp2f(sa[2 * k] - m_r);
        float a1 = exp2f(sa[2 * k + 1] - m_r);
        float b0 = exp2f(sb[2 * k] - m_r);
        float b1 = exp2f(sb[2 * k + 1] - m_r);
        rs0 += a0; rs1 += a1; rs2 += b0; rs3 += b1;
        wpkA[k] = cvt_pk_bf16(a0, a1);
        wpkB[k] = cvt_pk_bf16(b0, b1);
      }
      float rs = (rs0 + rs1) + (rs2 + rs3);
      rs += __shfl_xor(rs, 32);
      l_r += rs;
    }
    short8 paA[2], paB[2];
#pragma unroll
    for (int v = 0; v < 2; ++v) {
      {
        unsigned a0 = wpkA[4 * v], a1 = wpkA[4 * v + 1];
        unsigned b0 = wpkA[4 * v + 2], b1 = wpkA[4 * v + 3];
        unsigned own0 = h ? b0 : a0, own1 = h ? b1 : a1;
        unsigned snd0 = h ? a0 : b0, snd1 = h ? a1 : b1;
        unsigned rcv0 = __shfl_xor((int)snd0, 32), rcv1 = __shfl_xor((int)snd1, 32);
        unsigned lo0 = h ? rcv0 : own0, lo1 = h ? rcv1 : own1;
        unsigned hi0 = h ? own0 : rcv0, hi1 = h ? own1 : rcv1;
        uint4v u = {lo0, lo1, hi0, hi1};
        paA[v] = *(short8*)&u;
      }
      {
        unsigned a0 = wpkB[4 * v], a1 = wpkB[4 * v + 1];
        unsigned b0 = wpkB[4 * v + 2], b1 = wpkB[4 * v + 3];
        unsigned own0 = h ? b0 : a0, own1 = h ? b1 : a1;
        unsigned snd0 = h ? a0 : b0, snd1 = h ? a1 : b1;
        unsigned rcv0 = __shfl_xor((int)snd0, 32), rcv1 = __shfl_xor((int)snd1, 32);
        unsigned lo0 = h ? rcv0 : own0, lo1 = h ? rcv1 : own1;
        unsigned hi0 = h ? own0 : rcv0, hi1 = h ? own1 : rcv1;
        uint4v u = {lo0, lo1, hi0, hi1};
        paB[v] = *(short8*)&u;
      }
    }

#pragma unroll
    for (int nn = 0; nn < 8; ++nn) {
      const int d = 32 * nn + ql;
      const int dbase = d * 128, dswz = (d & 7) << 4;
      short8 bv0 = *(const short8*)(vt + ((dbase + 0 * 32 + 16 * h) ^ dswz));
      o[nn] = mfma32(paA[0], bv0, o[nn]);
      short8 bv1 = *(const short8*)(vt + ((dbase + 1 * 32 + 16 * h) ^ dswz));
      o[nn] = mfma32(paA[1], bv1, o[nn]);
      short8 bv2 = *(const short8*)(vt + ((dbase + 2 * 32 + 16 * h) ^ dswz));
      o[nn] = mfma32(paB[0], bv2, o[nn]);
      short8 bv3 = *(const short8*)(vt + ((dbase + 3 * 32 + 16 * h) ^ dswz));
      o[nn] = mfma32(paB[1], bv3, o[nn]);
    }

    asm volatile("s_waitcnt lgkmcnt(0)" ::: "memory");
    __builtin_amdgcn_s_barrier();
    __builtin_amdgcn_sched_barrier(0);
  }

  const long rowb = (long)b * LQ + qrow0;
#pragma unroll
  for (int rr = 0; rr < 16; ++rr) {
    long grow = rowb + (rr & 3) + 8 * (rr >> 2) + 4 * h;
    float* dst = Opart + ((long)ch * ROWS + grow) * 256 + ql;
#pragma unroll
    for (int nn = 0; nn < 8; ++nn) dst[32 * nn] = o[nn][rr];
  }
  if (h == 0) {
    Mb[(long)ch * ROWS + rowb + ql] = m_r;
    Lb[(long)ch * ROWS + rowb + ql] = l_r;
  }
}

// ---------------- launcher ----------------
extern "C" void kernel_launch(void* const* d_in, const int* in_sizes, int n_in,
                              void* d_out, int out_size, void* d_ws, size_t ws_size,
                              hipStream_t stream) {
  const float* query = (const float*)d_in[0];
  const float* key   = (const float*)d_in[1];
  const float* value = (const float*)d_in[2];
  const float* Wk  = (const float*)d_in[3];
  const float* bk  = (const float*)d_in[4];
  const float* Wv  = (const float*)d_in[5];
  const float* bv  = (const float*)d_in[6];
  const float* Wo  = (const float*)d_in[7];
  const float* bo  = (const float*)d_in[8];
  const float* g1  = (const float*)d_in[9];
  const float* b1  = (const float*)d_in[10];
  const float* g2  = (const float*)d_in[11];
  const float* b2  = (const float*)d_in[12];
  const float* W1  = (const float*)d_in[13];
  const float* bf1 = (const float*)d_in[14];
  const float* W2  = (const float*)d_in[15];
  const float* bf2 = (const float*)d_in[16];

  char* ws = (char*)d_ws;
  size_t off = 0;
  auto take = [&](size_t bytes) { char* p = ws + off; off += bytes; return p; };
  short* WkT = (short*)take((size_t)256 * 256 * 2);
  short* WvT = (short*)take((size_t)256 * 256 * 2);
  short* WoT = (short*)take((size_t)256 * 256 * 2);
  short* W1T = (short*)take((size_t)1024 * 256 * 2);
  short* W2T = (short*)take((size_t)256 * 1024 * 2);
  short* Kb  = (short*)take((size_t)NB * LKV * DQ * 2);   // dead after flash -> Hb aliases
  short* Vt  = (short*)take((size_t)NB * DQ * LKV * 2);
  float* Opart = (float*)take((size_t)NCHUNK * ROWS * 256 * 4);
  float* Mbuf  = (float*)take((size_t)NCHUNK * ROWS * 4);
  float* Lbuf  = (float*)take((size_t)NCHUNK * ROWS * 4);
  float* Xf    = (float*)take((size_t)ROWS * 256 * 4);
  short* Xb    = (short*)take((size_t)ROWS * 256 * 2);    // own buffer (gemmln reads Opart while writing Xb)
  short* Hb  = (short*)Kb;               // FF1 out 33.6MB aliases Kb+Vt region (dead)
  (void)ws_size; (void)in_sizes; (void)n_in; (void)out_size;

  dim3 blk(256);
  transpose_all<<<dim3(704), dim3(32, 8), 0, stream>>>(
      Wk, Wv, Wo, W1, W2, WkT, WvT, WoT, W1T, W2T);

  // K' = key @ Wk + bk   -> Kb [B*LKV][256] bf16   (A: f32 reg, B: bf16 gload)
  gemm128<1, 0, 0><<<dim3(2, 256, 1), blk, 0, stream>>>(
      key, 0, 256, WkT, 0, 256, bk, Kb, 0, 256, 256);
  // V'^T = (value @ Wv + bv)^T -> Vt [B][256][LKV] bf16  (A = WvT gload, B = value f32)
  gemm128<0, 1, 1><<<dim3(32, 2, 8), blk, 0, stream>>>(
      WvT, 0, 256, value, (long)LKV * 256, 256, bv, Vt, (long)256 * LKV, LKV, 256);
  // attention (KV-split 2, swapped-QK^T 32x32, batched subtiles, dbuf, XCD-pinned)
  flash_attn<<<dim3(256), blk, 0, stream>>>(query, Kb, Vt, Opart, Mbuf, Lbuf);
  // x = LN1(combine(Opart) @ Wo + bo + query) -> Xf f32 + Xb bf16 (combine+LN fused)
  gemmln<2, true><<<dim3(ROWS / 64), blk, 0, stream>>>(
      Opart, WoT, bo, query, Mbuf, Lbuf, g1, b1, Xf, Xb, 256);
  // h = relu(x @ W1 + bf1) -> Hb bf16  (both operands gload)
  gemm128<0, 0, 3><<<dim3(8, 128, 1), blk, 0, stream>>>(
      Xb, 0, 256, W1T, 0, 256, bf1, Hb, 0, 1024, 256);
  // out = LN2(h @ W2 + bf2 + x) -> d_out f32  (LN fused)
  gemmln<0, false><<<dim3(ROWS / 64), blk, 0, stream>>>(
      Hb, W2T, bf2, Xf, nullptr, nullptr, g2, b2, (float*)d_out, nullptr, 1024);
}

// Round 15
// 225.896 us; speedup vs baseline: 1.5607x; 1.0060x over previous
//
#include <hip/hip_runtime.h>
#include <stdint.h>

// ---------------- types / helpers ----------------
typedef __attribute__((ext_vector_type(4))) float f32x4;
typedef __attribute__((ext_vector_type(16))) float f32x16;
typedef __attribute__((ext_vector_type(8))) short short8;
typedef __attribute__((ext_vector_type(4))) short short4v;
typedef __attribute__((ext_vector_type(4))) unsigned uint4v;

__device__ __forceinline__ short f2bf(float f) {
  union { float f; uint32_t u; } v; v.f = f;
  uint32_t r = v.u + 0x7FFFu + ((v.u >> 16) & 1u);
  return (short)(r >> 16);
}

__device__ __forceinline__ unsigned cvt_pk_bf16(float lo, float hi) {
  unsigned r;
  asm("v_cvt_pk_bf16_f32 %0, %1, %2" : "=v"(r) : "v"(lo), "v"(hi));
  return r;
}

// v_permlane32_swap_b32 X, Y: X' = {X.lo, Y.lo}, Y' = {X.hi, Y.hi}.
// ONLY safe when X and Y are guaranteed-distinct registers (distinct producer
// values). R13/R14 lesson: the copy-then-swap reduction pattern
// (float t = x; pl32swap(t, x)) can alias both "+v" operands to ONE VGPR ->
// in-place half-swap, reduction degenerates -> absmax 0.14 FAIL. Reductions
// use __shfl_xor; permlane is reserved for the pack path (distinct cvt_pk outputs).
__device__ __forceinline__ void pl32swap(unsigned& x, unsigned& y) {
  asm volatile("v_permlane32_swap_b32 %0, %1" : "+v"(x), "+v"(y));
}

__device__ __forceinline__ f32x4 mfma16(short8 a, short8 b, f32x4 c) {
  return __builtin_amdgcn_mfma_f32_16x16x32_bf16(a, b, c, 0, 0, 0);
}
__device__ __forceinline__ f32x16 mfma32(short8 a, short8 b, f32x16 c) {
  return __builtin_amdgcn_mfma_f32_32x32x16_bf16(a, b, c, 0, 0, 0);
}

#define NB 8
#define LQ 2048
#define LKV 4096
#define DQ 256
#define FF 1024
#define NCHUNK 2
#define ROWS (NB * LQ)   // 16384

#define AS1(p) ((const __attribute__((address_space(1))) void*)(p))
#define AS3(p) ((__attribute__((address_space(3))) void*)(p))

// ---------------- all weight transposes in ONE launch ----------------
__global__ void transpose_all(
    const float* __restrict__ Wk, const float* __restrict__ Wv,
    const float* __restrict__ Wo, const float* __restrict__ W1,
    const float* __restrict__ W2,
    short* __restrict__ WkT, short* __restrict__ WvT, short* __restrict__ WoT,
    short* __restrict__ W1T, short* __restrict__ W2T) {
  __shared__ float t[32][33];
  int bid = blockIdx.x;
  const float* in; short* out; int R, C, b0;
  if (bid < 64)       { in = Wk; out = WkT; R = 256;  C = 256;  b0 = bid; }
  else if (bid < 128) { in = Wv; out = WvT; R = 256;  C = 256;  b0 = bid - 64; }
  else if (bid < 192) { in = Wo; out = WoT; R = 256;  C = 256;  b0 = bid - 128; }
  else if (bid < 448) { in = W1; out = W1T; R = 256;  C = 1024; b0 = bid - 192; }
  else                { in = W2; out = W2T; R = 1024; C = 256;  b0 = bid - 448; }
  int nbx = C / 32;
  int c0 = (b0 % nbx) * 32, r0 = (b0 / nbx) * 32;
  int tx = threadIdx.x, ty = threadIdx.y;  // 32 x 8
#pragma unroll
  for (int dy = 0; dy < 32; dy += 8)
    t[ty + dy][tx] = in[(long)(r0 + ty + dy) * C + c0 + tx];
  __syncthreads();
#pragma unroll
  for (int dy = 0; dy < 32; dy += 8)
    out[(long)(c0 + ty + dy) * R + r0 + tx] = f2bf(t[tx][ty + dy]);
}

// ---------------- generic GEMM: C[M,N] = A[M,K] * B[N,K]^T (+epilogues) ----------------
// Tile 128x128, BK=64, 4 waves. AMODE/BMODE: 0 = bf16 via global_load_lds; 1 = f32 reg+cvt_pk.
// EPI: 0 = bf16 + bias[col]; 1 = bf16 + bias[row]; 3 = relu bf16 + bias[col]
template <int AMODE, int BMODE, int EPI>
__global__ void __launch_bounds__(256, 2) gemm128(
    const void* __restrict__ A, long sAb, int lda,
    const void* __restrict__ B, long sBb, int ldb,
    const float* __restrict__ bias,
    void* C, long sCb, int ldc, int K) {
  __shared__ char lds[32768];
  const int tid = threadIdx.x;
  const int bn = blockIdx.x, bm = blockIdx.y, bz = blockIdx.z;
  const int w = tid >> 6, l = tid & 63;
  const int wm = w & 1, wn = w >> 1;
  const int lr = l & 15, lq = l >> 4;

  auto stageReg = [&](const float* src, int ld, long row0, int k0, char* ldsb) {
#pragma unroll
    for (int it = 0; it < 4; ++it) {
      int idx = it * 2048 + tid * 8;
      int r = idx >> 6, c = idx & 63;
      const float* p = src + (row0 + r) * (long)ld + k0 + c;
      f32x4 f0 = *(const f32x4*)p, f1 = *(const f32x4*)(p + 4);
      uint4v u;
      u[0] = cvt_pk_bf16(f0[0], f0[1]); u[1] = cvt_pk_bf16(f0[2], f0[3]);
      u[2] = cvt_pk_bf16(f1[0], f1[1]); u[3] = cvt_pk_bf16(f1[2], f1[3]);
      *(short8*)(ldsb + ((r * 128 + c * 2) ^ ((r & 7) << 4))) = *(short8*)&u;
    }
  };
  auto stageGld = [&](const short* src, int ld, long row0, int k0, char* ldsb) {
#pragma unroll
    for (int it = 0; it < 4; ++it) {
      const int span = it * 4096 + w * 1024;     // wave-uniform
      int idx = (span >> 4) + l;                 // chunk index
      int r = idx >> 3, c = idx & 7;
      __builtin_amdgcn_global_load_lds(
          AS1(src + (row0 + r) * (long)ld + k0 + ((c ^ (r & 7)) * 8)),
          AS3(ldsb + span), 16, 0, 0);
    }
  };

  f32x4 acc[4][4] = {};
  for (int k0 = 0; k0 < K; k0 += 64) {
    if (AMODE == 0)      stageGld((const short*)A + sAb * bz, lda, (long)bm * 128, k0, lds);
    else                 stageReg((const float*)A + sAb * bz, lda, (long)bm * 128, k0, lds);
    if (BMODE == 0)      stageGld((const short*)B + sBb * bz, ldb, (long)bn * 128, k0, lds + 16384);
    else                 stageReg((const float*)B + sBb * bz, ldb, (long)bn * 128, k0, lds + 16384);
    __syncthreads();
    short8 af[4][2], bfr[4][2];
#pragma unroll
    for (int i = 0; i < 4; ++i) {
#pragma unroll
      for (int kk = 0; kk < 2; ++kk) {
        int ra = wm * 64 + i * 16 + lr;
        af[i][kk] = *(const short8*)(lds + ((ra * 128 + (kk * 32 + lq * 8) * 2) ^ ((ra & 7) << 4)));
        int rb = wn * 64 + i * 16 + lr;
        bfr[i][kk] = *(const short8*)(lds + 16384 + ((rb * 128 + (kk * 32 + lq * 8) * 2) ^ ((rb & 7) << 4)));
      }
    }
#pragma unroll
    for (int i = 0; i < 4; ++i)
#pragma unroll
      for (int j = 0; j < 4; ++j) {
        acc[i][j] = mfma16(af[i][0], bfr[j][0], acc[i][j]);
        acc[i][j] = mfma16(af[i][1], bfr[j][1], acc[i][j]);
      }
    __syncthreads();
  }
#pragma unroll
  for (int i = 0; i < 4; ++i) {
#pragma unroll
    for (int j = 0; j < 4; ++j) {
#pragma unroll
      for (int r = 0; r < 4; ++r) {
        long row = (long)bm * 128 + wm * 64 + i * 16 + lq * 4 + r;
        long col = (long)bn * 128 + wn * 64 + j * 16 + lr;
        float v = acc[i][j][r];
        if (EPI == 0) {
          v += bias[col];
          ((short*)C + sCb * bz)[row * ldc + col] = f2bf(v);
        } else if (EPI == 1) {
          v += bias[row];
          ((short*)C + sCb * bz)[row * ldc + col] = f2bf(v);
        } else {
          v += bias[col];
          v = fmaxf(v, 0.f);
          ((short*)C + sCb * bz)[row * ldc + col] = f2bf(v);
        }
      }
    }
  }
}

// ---------------- GEMM + fused LayerNorm: C[M,256] = A[M,K] * B[256,K]^T ----------------
// Tile 64 rows x 256 cols (FULL width -> LN per row stays in-block). 4 waves x 16 rows.
// AMODE: 0 = bf16 A via global_load_lds; 2 = combine two f32 Opart planes (softmax merge).
template <int AMODE, bool WB16>
__global__ void __launch_bounds__(256, 2) gemmln(
    const void* __restrict__ A, const short* __restrict__ Bw,
    const float* __restrict__ bias, const float* __restrict__ resid,
    const float* __restrict__ Mcomb, const float* __restrict__ Lcomb,
    const float* __restrict__ g, const float* __restrict__ be,
    float* __restrict__ outF, short* __restrict__ outB, int K) {
  __shared__ char lds[40960];    // A 8KB @0, B 32KB @8192
  const int tid = threadIdx.x;
  const int bm = blockIdx.x;     // 256 blocks x 64 rows
  const int w = tid >> 6, l = tid & 63;
  const int lr = l & 15, lq = l >> 4;
  char* ldsA = lds;
  char* ldsB = lds + 8192;

  f32x4 acc[16] = {};
  for (int k0 = 0; k0 < K; k0 += 64) {
    // ---- stage A tile [64][64] ----
    if (AMODE == 0) {
      const short* src = (const short*)A;
#pragma unroll
      for (int it = 0; it < 2; ++it) {
        const int span = it * 4096 + w * 1024;
        int idx = (span >> 4) + l;
        int r = idx >> 3, c = idx & 7;
        __builtin_amdgcn_global_load_lds(
            AS1(src + ((long)bm * 64 + r) * K + k0 + ((c ^ (r & 7)) * 8)),
            AS3(ldsA + span), 16, 0, 0);
      }
    } else {
      const float* O0 = (const float*)A;
#pragma unroll
      for (int it = 0; it < 2; ++it) {
        int idx = it * 2048 + tid * 8;
        int r = idx >> 6, c = idx & 63;
        long row = (long)bm * 64 + r;
        float m0 = Mcomb[row], m1 = Mcomb[ROWS + row];
        float l0 = Lcomb[row], l1 = Lcomb[ROWS + row];
        float M = fmaxf(m0, m1);
        float e0 = exp2f(m0 - M), e1 = exp2f(m1 - M);
        float inv = 1.f / (e0 * l0 + e1 * l1);
        float w0 = e0 * inv, w1 = e1 * inv;
        const float* p0 = O0 + row * 256 + k0 + c;
        const float* p1 = p0 + (long)ROWS * 256;
        f32x4 a0 = *(const f32x4*)p0, a1 = *(const f32x4*)(p0 + 4);
        f32x4 b0 = *(const f32x4*)p1, b1 = *(const f32x4*)(p1 + 4);
        uint4v u;
        u[0] = cvt_pk_bf16(w0 * a0[0] + w1 * b0[0], w0 * a0[1] + w1 * b0[1]);
        u[1] = cvt_pk_bf16(w0 * a0[2] + w1 * b0[2], w0 * a0[3] + w1 * b0[3]);
        u[2] = cvt_pk_bf16(w0 * a1[0] + w1 * b1[0], w0 * a1[1] + w1 * b1[1]);
        u[3] = cvt_pk_bf16(w0 * a1[2] + w1 * b1[2], w0 * a1[3] + w1 * b1[3]);
        *(short8*)(ldsA + ((r * 128 + c * 2) ^ ((r & 7) << 4))) = *(short8*)&u;
      }
    }
    // ---- stage B tile [256][64] ----
#pragma unroll
    for (int it = 0; it < 8; ++it) {
      const int span = it * 4096 + w * 1024;
      int idx = (span >> 4) + l;
      int r = idx >> 3, c = idx & 7;
      __builtin_amdgcn_global_load_lds(
          AS1(Bw + (long)r * K + k0 + ((c ^ (r & 7)) * 8)),
          AS3(ldsB + span), 16, 0, 0);
    }
    __syncthreads();
    short8 af0, af1;
    {
      int ra = w * 16 + lr;
      af0 = *(const short8*)(ldsA + ((ra * 128 + (lq * 8) * 2) ^ ((ra & 7) << 4)));
      af1 = *(const short8*)(ldsA + ((ra * 128 + (32 + lq * 8) * 2) ^ ((ra & 7) << 4)));
    }
#pragma unroll
    for (int j = 0; j < 16; ++j) {
      int rb = j * 16 + lr;
      short8 b0 = *(const short8*)(ldsB + ((rb * 128 + (lq * 8) * 2) ^ ((rb & 7) << 4)));
      short8 b1 = *(const short8*)(ldsB + ((rb * 128 + (32 + lq * 8) * 2) ^ ((rb & 7) << 4)));
      acc[j] = mfma16(af0, b0, acc[j]);
      acc[j] = mfma16(af1, b1, acc[j]);
    }
    __syncthreads();
  }

  // ---- epilogue: bias + resid, LN over each row, write ----
  const long rowbase = (long)bm * 64 + w * 16;
  float bia[16], gg[16], bb[16];
#pragma unroll
  for (int j = 0; j < 16; ++j) {
    int col = j * 16 + lr;
    bia[j] = bias[col]; gg[j] = g[col]; bb[j] = be[col];
  }
#pragma unroll
  for (int r = 0; r < 4; ++r) {
    long row = rowbase + lq * 4 + r;
    float v[16];
    float s = 0.f, s2 = 0.f;
#pragma unroll
    for (int j = 0; j < 16; ++j) {
      float x = acc[j][r] + bia[j] + resid[row * 256 + j * 16 + lr];
      v[j] = x; s += x; s2 += x * x;
    }
#pragma unroll
    for (int mk = 1; mk < 16; mk <<= 1) { s += __shfl_xor(s, mk); s2 += __shfl_xor(s2, mk); }
    float mu = s * (1.f / 256.f);
    float var = s2 * (1.f / 256.f) - mu * mu;
    float rstd = rsqrtf(var + 1e-5f);
#pragma unroll
    for (int j = 0; j < 16; ++j) {
      int col = j * 16 + lr;
      float y = (v[j] - mu) * rstd * gg[j] + bb[j];
      outF[row * 256 + col] = y;
      if (WB16) outB[row * 256 + col] = f2bf(y);
    }
  }
}

// ---------------- flash attention: swapped-QK^T 32x32, permlane pack, dbuf ----------------
// grid 256 (1 block/CU), n&7 = batch = XCD slot (per-XCD KV = 4MB = L2). Block 256 =
// 4 waves, wave owns 32 q rows. LDS: 2 x (K 32KB + V^T 32KB) = 128KB, counted vmcnt(16).
// 1 wave/SIMD (register-locked). Permlane ONLY in the pack path (distinct registers);
// pmax/rs cross-half reductions use __shfl_xor (R13/R14 lesson: copy-then-swap can
// alias "+v" operands to one VGPR -> in-place swap -> corrupted reductions -> 0.14 FAIL).
__global__ void __launch_bounds__(256, 1) flash_attn(
    const float* __restrict__ Q, const short* __restrict__ Kb,
    const short* __restrict__ Vt, float* __restrict__ Opart,
    float* __restrict__ Mb, float* __restrict__ Lb) {
  __shared__ char lds[131072];
  const int tid = threadIdx.x;
  const int n = blockIdx.x;
  const int b = n & 7;           // XCD-local batch
  const int slot = n >> 3;       // [0,32)
  const int qt = slot & 15;
  const int ch = slot >> 4;      // [0,2)
  const int wid = tid >> 6, l = tid & 63;
  const int ql = l & 31, h = l >> 5;
  const int qrow0 = qt * 128 + wid * 32;
  const float* Qp = Q + ((long)b * LQ + qrow0 + ql) * DQ;
  const short* Kp = Kb + (long)b * LKV * DQ;
  const short* Vp = Vt + (long)b * DQ * LKV;
  const float SCQ = 0.0625f * 1.4426950408889634f;  // folded into Q cast

  auto stage = [&](int bufb, int kv0) {
    char* kqb = lds + bufb * 65536;
    char* vtb = kqb + 32768;
#pragma unroll
    for (int i = 0; i < 8; ++i) {
      const int j = wid * 8192 + i * 1024;       // wave-uniform LDS span base
      {
        int r = (j >> 9) + (l >> 5);
        int cc = l & 31;
        const short* gk = Kp + (long)(kv0 + r) * DQ + ((cc ^ (r & 15)) * 8);
        __builtin_amdgcn_global_load_lds(AS1(gk), AS3(kqb + j), 16, 0, 0);
      }
      {
        int d = (j >> 7) + (l >> 3);
        int cc = l & 7;
        const short* gv = Vp + (long)d * LKV + kv0 + ((cc ^ (d & 7)) * 8);
        __builtin_amdgcn_global_load_lds(AS1(gv), AS3(vtb + j), 16, 0, 0);
      }
    }
  };

  short8 qf[16];
#pragma unroll
  for (int w = 0; w < 16; ++w) {
    const float* p = Qp + w * 16 + h * 8;
    f32x4 f0 = *(const f32x4*)p, f1 = *(const f32x4*)(p + 4);
    short8 v;
#pragma unroll
    for (int j = 0; j < 4; ++j) { v[j] = f2bf(f0[j] * SCQ); v[4 + j] = f2bf(f1[j] * SCQ); }
    qf[w] = v;
  }

  f32x16 o[8] = {};
  float m_r = -1e30f, l_r = 0.f;

  const int kv_lo = ch * (LKV / NCHUNK);
  const int NT = (LKV / NCHUNK) / 64;   // 32 tiles

  stage(0, kv_lo);

  for (int t = 0; t < NT; ++t) {
    if (t + 1 < NT) {
      stage((t + 1) & 1, kv_lo + (t + 1) * 64);
      asm volatile("s_waitcnt vmcnt(16)" ::: "memory");
    } else {
      asm volatile("s_waitcnt vmcnt(0)" ::: "memory");
    }
    __builtin_amdgcn_s_barrier();
    __builtin_amdgcn_sched_barrier(0);
    char* kq = lds + (t & 1) * 65536;
    char* vt = kq + 32768;

    // ---- QK^T both 32-kv subtiles: two independent MFMA chains, interleaved ----
    f32x16 sa = {}, sb = {};
    {
      const int krA = ql, krB = 32 + ql;
      const int baseA = krA * 512, swzA = (krA & 15) << 4;
      const int baseB = krB * 512, swzB = (krB & 15) << 4;
#pragma unroll
      for (int w = 0; w < 16; ++w) {
        short8 kfA = *(const short8*)(kq + ((baseA + w * 32 + h * 16) ^ swzA));
        sa = mfma32(kfA, qf[w], sa);
        short8 kfB = *(const short8*)(kq + ((baseB + w * 32 + h * 16) ^ swzB));
        sb = mfma32(kfB, qf[w], sb);
      }
    }

    // ---- tree-max (depth 5) + shfl_xor cross-half + single deferred rescale ----
    {
      float m8[8];
#pragma unroll
      for (int i = 0; i < 8; ++i)
        m8[i] = fmaxf(fmaxf(sa[i], sa[i + 8]), fmaxf(sb[i], sb[i + 8]));
      float m0 = fmaxf(fmaxf(m8[0], m8[1]), fmaxf(m8[2], m8[3]));
      float m1 = fmaxf(fmaxf(m8[4], m8[5]), fmaxf(m8[6], m8[7]));
      float pmax = fmaxf(m0, m1);
      pmax = fmaxf(pmax, __shfl_xor(pmax, 32));
      if (__any(pmax > m_r + 8.f)) {
        float mn = fmaxf(m_r, pmax);
        float alpha = exp2f(m_r - mn);
        m_r = mn;
        l_r *= alpha;
#pragma unroll
        for (int rr = 0; rr < 16; ++rr) {
          int src = ((rr & 3) + 8 * (rr >> 2) + 4 * h) + 32 * h;
          float ar = __shfl(alpha, src);
#pragma unroll
          for (int nn = 0; nn < 8; ++nn) o[nn][rr] *= ar;
        }
      }
    }

    // ---- exp2 + pack; A-frags via permlane32_swap on DISTINCT registers ----
    short8 paA[2], paB[2];
    float rs0 = 0.f, rs1 = 0.f, rs2 = 0.f, rs3 = 0.f;
    {
      float pA[16];
#pragma unroll
      for (int i = 0; i < 16; ++i) pA[i] = exp2f(sa[i] - m_r);
#pragma unroll
      for (int i = 0; i < 4; ++i) { rs0 += pA[4 * i]; rs1 += pA[4 * i + 1]; rs2 += pA[4 * i + 2]; rs3 += pA[4 * i + 3]; }
#pragma unroll
      for (int v = 0; v < 2; ++v) {
        unsigned w01 = cvt_pk_bf16(pA[8 * v + 0], pA[8 * v + 1]);
        unsigned w23 = cvt_pk_bf16(pA[8 * v + 2], pA[8 * v + 3]);
        unsigned w45 = cvt_pk_bf16(pA[8 * v + 4], pA[8 * v + 5]);
        unsigned w67 = cvt_pk_bf16(pA[8 * v + 6], pA[8 * v + 7]);
        pl32swap(w01, w45);   // w01 -> word0, w45 -> word2
        pl32swap(w23, w67);   // w23 -> word1, w67 -> word3
        uint4v u = {w01, w23, w45, w67};
        paA[v] = *(short8*)&u;
      }
    }
    {
      float pB[16];
#pragma unroll
      for (int i = 0; i < 16; ++i) pB[i] = exp2f(sb[i] - m_r);
#pragma unroll
      for (int i = 0; i < 4; ++i) { rs0 += pB[4 * i]; rs1 += pB[4 * i + 1]; rs2 += pB[4 * i + 2]; rs3 += pB[4 * i + 3]; }
#pragma unroll
      for (int v = 0; v < 2; ++v) {
        unsigned w01 = cvt_pk_bf16(pB[8 * v + 0], pB[8 * v + 1]);
        unsigned w23 = cvt_pk_bf16(pB[8 * v + 2], pB[8 * v + 3]);
        unsigned w45 = cvt_pk_bf16(pB[8 * v + 4], pB[8 * v + 5]);
        unsigned w67 = cvt_pk_bf16(pB[8 * v + 6], pB[8 * v + 7]);
        pl32swap(w01, w45);
        pl32swap(w23, w67);
        uint4v u = {w01, w23, w45, w67};
        paB[v] = *(short8*)&u;
      }
    }
    {
      float rs = (rs0 + rs1) + (rs2 + rs3);
      rs += __shfl_xor(rs, 32);
      l_r += rs;
    }

    // ---- O += P V' for both subtiles: 8 o-chains x 4 mfma (ILP) ----
#pragma unroll
    for (int nn = 0; nn < 8; ++nn) {
      const int d = 32 * nn + ql;
      const int dbase = d * 128, dswz = (d & 7) << 4;
      short8 bv0 = *(const short8*)(vt + ((dbase + 0 * 32 + 16 * h) ^ dswz));
      o[nn] = mfma32(paA[0], bv0, o[nn]);
      short8 bv1 = *(const short8*)(vt + ((dbase + 1 * 32 + 16 * h) ^ dswz));
      o[nn] = mfma32(paA[1], bv1, o[nn]);
      short8 bv2 = *(const short8*)(vt + ((dbase + 2 * 32 + 16 * h) ^ dswz));
      o[nn] = mfma32(paB[0], bv2, o[nn]);
      short8 bv3 = *(const short8*)(vt + ((dbase + 3 * 32 + 16 * h) ^ dswz));
      o[nn] = mfma32(paB[1], bv3, o[nn]);
    }

    asm volatile("s_waitcnt lgkmcnt(0)" ::: "memory");
    __builtin_amdgcn_s_barrier();
    __builtin_amdgcn_sched_barrier(0);
  }

  // epilogue: unnormalized partial O (f32) + per-row m,l
  const long rowb = (long)b * LQ + qrow0;
#pragma unroll
  for (int rr = 0; rr < 16; ++rr) {
    long grow = rowb + (rr & 3) + 8 * (rr >> 2) + 4 * h;
    float* dst = Opart + ((long)ch * ROWS + grow) * 256 + ql;
#pragma unroll
    for (int nn = 0; nn < 8; ++nn) dst[32 * nn] = o[nn][rr];
  }
  if (h == 0) {
    Mb[(long)ch * ROWS + rowb + ql] = m_r;
    Lb[(long)ch * ROWS + rowb + ql] = l_r;
  }
}

// ---------------- launcher ----------------
extern "C" void kernel_launch(void* const* d_in, const int* in_sizes, int n_in,
                              void* d_out, int out_size, void* d_ws, size_t ws_size,
                              hipStream_t stream) {
  const float* query = (const float*)d_in[0];
  const float* key   = (const float*)d_in[1];
  const float* value = (const float*)d_in[2];
  const float* Wk  = (const float*)d_in[3];
  const float* bk  = (const float*)d_in[4];
  const float* Wv  = (const float*)d_in[5];
  const float* bv  = (const float*)d_in[6];
  const float* Wo  = (const float*)d_in[7];
  const float* bo  = (const float*)d_in[8];
  const float* g1  = (const float*)d_in[9];
  const float* b1  = (const float*)d_in[10];
  const float* g2  = (const float*)d_in[11];
  const float* b2  = (const float*)d_in[12];
  const float* W1  = (const float*)d_in[13];
  const float* bf1 = (const float*)d_in[14];
  const float* W2  = (const float*)d_in[15];
  const float* bf2 = (const float*)d_in[16];

  char* ws = (char*)d_ws;
  size_t off = 0;
  auto take = [&](size_t bytes) { char* p = ws + off; off += bytes; return p; };
  short* WkT = (short*)take((size_t)256 * 256 * 2);
  short* WvT = (short*)take((size_t)256 * 256 * 2);
  short* WoT = (short*)take((size_t)256 * 256 * 2);
  short* W1T = (short*)take((size_t)1024 * 256 * 2);
  short* W2T = (short*)take((size_t)256 * 1024 * 2);
  short* Kb  = (short*)take((size_t)NB * LKV * DQ * 2);   // dead after flash -> Hb aliases
  short* Vt  = (short*)take((size_t)NB * DQ * LKV * 2);
  float* Opart = (float*)take((size_t)NCHUNK * ROWS * 256 * 4);   // f32 partials
  float* Mbuf  = (float*)take((size_t)NCHUNK * ROWS * 4);
  float* Lbuf  = (float*)take((size_t)NCHUNK * ROWS * 4);
  float* Xf    = (float*)take((size_t)ROWS * 256 * 4);
  short* Xb    = (short*)take((size_t)ROWS * 256 * 2);
  short* Hb  = (short*)Kb;               // FF1 out 33.6MB aliases Kb+Vt region (dead)
  (void)ws_size; (void)in_sizes; (void)n_in; (void)out_size;

  dim3 blk(256);
  transpose_all<<<dim3(704), dim3(32, 8), 0, stream>>>(
      Wk, Wv, Wo, W1, W2, WkT, WvT, WoT, W1T, W2T);

  // K' = key @ Wk + bk   -> Kb [B*LKV][256] bf16   (A: f32 reg, B: bf16 gload)
  gemm128<1, 0, 0><<<dim3(2, 256, 1), blk, 0, stream>>>(
      key, 0, 256, WkT, 0, 256, bk, Kb, 0, 256, 256);
  // V'^T = (value @ Wv + bv)^T -> Vt [B][256][LKV] bf16  (A = WvT gload, B = value f32)
  gemm128<0, 1, 1><<<dim3(32, 2, 8), blk, 0, stream>>>(
      WvT, 0, 256, value, (long)LKV * 256, 256, bv, Vt, (long)256 * LKV, LKV, 256);
  // attention (KV-split 2, swapped-QK^T 32x32, permlane pack, dbuf, XCD-pinned)
  flash_attn<<<dim3(256), blk, 0, stream>>>(query, Kb, Vt, Opart, Mbuf, Lbuf);
  // x = LN1(combine(Opart) @ Wo + bo + query) -> Xf f32 + Xb bf16 (combine+LN fused)
  gemmln<2, true><<<dim3(ROWS / 64), blk, 0, stream>>>(
      Opart, WoT, bo, query, Mbuf, Lbuf, g1, b1, Xf, Xb, 256);
  // h = relu(x @ W1 + bf1) -> Hb bf16  (both operands gload)
  gemm128<0, 0, 3><<<dim3(8, 128, 1), blk, 0, stream>>>(
      Xb, 0, 256, W1T, 0, 256, bf1, Hb, 0, 1024, 256);
  // out = LN2(h @ W2 + bf2 + x) -> d_out f32  (LN fused)
  gemmln<0, false><<<dim3(ROWS / 64), blk, 0, stream>>>(
      Hb, W2T, bf2, Xf, nullptr, nullptr, g2, b2, (float*)d_out, nullptr, 1024);
}

// Round 16
// 224.869 us; speedup vs baseline: 1.5678x; 1.0046x over previous
//
#include <hip/hip_runtime.h>
#include <stdint.h>

// ---------------- types / helpers ----------------
typedef __attribute__((ext_vector_type(4))) float f32x4;
typedef __attribute__((ext_vector_type(16))) float f32x16;
typedef __attribute__((ext_vector_type(8))) short short8;
typedef __attribute__((ext_vector_type(4))) short short4v;
typedef __attribute__((ext_vector_type(4))) unsigned uint4v;

__device__ __forceinline__ short f2bf(float f) {
  union { float f; uint32_t u; } v; v.f = f;
  uint32_t r = v.u + 0x7FFFu + ((v.u >> 16) & 1u);
  return (short)(r >> 16);
}

__device__ __forceinline__ float bf2f(short s) {
  union { unsigned u; float f; } v; v.u = ((unsigned)(unsigned short)s) << 16; return v.f;
}

__device__ __forceinline__ unsigned cvt_pk_bf16(float lo, float hi) {
  unsigned r;
  asm("v_cvt_pk_bf16_f32 %0, %1, %2" : "=v"(r) : "v"(lo), "v"(hi));
  return r;
}

// v_permlane32_swap_b32 X, Y: X' = {X.lo, Y.lo}, Y' = {X.hi, Y.hi}.
// ONLY safe when X and Y are guaranteed-distinct registers (distinct producer
// values). R13/R14 lesson: copy-then-swap reductions can alias both "+v"
// operands to ONE VGPR -> in-place swap -> corrupted reductions -> 0.14 FAIL.
// Reductions use __shfl_xor; permlane reserved for the pack path.
__device__ __forceinline__ void pl32swap(unsigned& x, unsigned& y) {
  asm volatile("v_permlane32_swap_b32 %0, %1" : "+v"(x), "+v"(y));
}

__device__ __forceinline__ f32x4 mfma16(short8 a, short8 b, f32x4 c) {
  return __builtin_amdgcn_mfma_f32_16x16x32_bf16(a, b, c, 0, 0, 0);
}
__device__ __forceinline__ f32x16 mfma32(short8 a, short8 b, f32x16 c) {
  return __builtin_amdgcn_mfma_f32_32x32x16_bf16(a, b, c, 0, 0, 0);
}

#define NB 8
#define LQ 2048
#define LKV 4096
#define DQ 256
#define FF 1024
#define NCHUNK 2
#define ROWS (NB * LQ)   // 16384

#define AS1(p) ((const __attribute__((address_space(1))) void*)(p))
#define AS3(p) ((__attribute__((address_space(3))) void*)(p))

// ---------------- all weight transposes in ONE launch ----------------
__global__ void transpose_all(
    const float* __restrict__ Wk, const float* __restrict__ Wv,
    const float* __restrict__ Wo, const float* __restrict__ W1,
    const float* __restrict__ W2,
    short* __restrict__ WkT, short* __restrict__ WvT, short* __restrict__ WoT,
    short* __restrict__ W1T, short* __restrict__ W2T) {
  __shared__ float t[32][33];
  int bid = blockIdx.x;
  const float* in; short* out; int R, C, b0;
  if (bid < 64)       { in = Wk; out = WkT; R = 256;  C = 256;  b0 = bid; }
  else if (bid < 128) { in = Wv; out = WvT; R = 256;  C = 256;  b0 = bid - 64; }
  else if (bid < 192) { in = Wo; out = WoT; R = 256;  C = 256;  b0 = bid - 128; }
  else if (bid < 448) { in = W1; out = W1T; R = 256;  C = 1024; b0 = bid - 192; }
  else                { in = W2; out = W2T; R = 1024; C = 256;  b0 = bid - 448; }
  int nbx = C / 32;
  int c0 = (b0 % nbx) * 32, r0 = (b0 / nbx) * 32;
  int tx = threadIdx.x, ty = threadIdx.y;  // 32 x 8
#pragma unroll
  for (int dy = 0; dy < 32; dy += 8)
    t[ty + dy][tx] = in[(long)(r0 + ty + dy) * C + c0 + tx];
  __syncthreads();
#pragma unroll
  for (int dy = 0; dy < 32; dy += 8)
    out[(long)(c0 + ty + dy) * R + r0 + tx] = f2bf(t[tx][ty + dy]);
}

// ---------------- generic GEMM: C[M,N] = A[M,K] * B[N,K]^T (+epilogues) ----------------
// Tile 128x128, BK=64, 4 waves. AMODE/BMODE: 0 = bf16 via global_load_lds; 1 = f32 reg+cvt_pk.
// EPI: 0 = bf16 + bias[col]; 1 = bf16 + bias[row]; 3 = relu bf16 + bias[col]
template <int AMODE, int BMODE, int EPI>
__global__ void __launch_bounds__(256, 2) gemm128(
    const void* __restrict__ A, long sAb, int lda,
    const void* __restrict__ B, long sBb, int ldb,
    const float* __restrict__ bias,
    void* C, long sCb, int ldc, int K) {
  __shared__ char lds[32768];
  const int tid = threadIdx.x;
  const int bn = blockIdx.x, bm = blockIdx.y, bz = blockIdx.z;
  const int w = tid >> 6, l = tid & 63;
  const int wm = w & 1, wn = w >> 1;
  const int lr = l & 15, lq = l >> 4;

  auto stageReg = [&](const float* src, int ld, long row0, int k0, char* ldsb) {
#pragma unroll
    for (int it = 0; it < 4; ++it) {
      int idx = it * 2048 + tid * 8;
      int r = idx >> 6, c = idx & 63;
      const float* p = src + (row0 + r) * (long)ld + k0 + c;
      f32x4 f0 = *(const f32x4*)p, f1 = *(const f32x4*)(p + 4);
      uint4v u;
      u[0] = cvt_pk_bf16(f0[0], f0[1]); u[1] = cvt_pk_bf16(f0[2], f0[3]);
      u[2] = cvt_pk_bf16(f1[0], f1[1]); u[3] = cvt_pk_bf16(f1[2], f1[3]);
      *(short8*)(ldsb + ((r * 128 + c * 2) ^ ((r & 7) << 4))) = *(short8*)&u;
    }
  };
  auto stageGld = [&](const short* src, int ld, long row0, int k0, char* ldsb) {
#pragma unroll
    for (int it = 0; it < 4; ++it) {
      const int span = it * 4096 + w * 1024;     // wave-uniform
      int idx = (span >> 4) + l;                 // chunk index
      int r = idx >> 3, c = idx & 7;
      __builtin_amdgcn_global_load_lds(
          AS1(src + (row0 + r) * (long)ld + k0 + ((c ^ (r & 7)) * 8)),
          AS3(ldsb + span), 16, 0, 0);
    }
  };

  f32x4 acc[4][4] = {};
  for (int k0 = 0; k0 < K; k0 += 64) {
    if (AMODE == 0)      stageGld((const short*)A + sAb * bz, lda, (long)bm * 128, k0, lds);
    else                 stageReg((const float*)A + sAb * bz, lda, (long)bm * 128, k0, lds);
    if (BMODE == 0)      stageGld((const short*)B + sBb * bz, ldb, (long)bn * 128, k0, lds + 16384);
    else                 stageReg((const float*)B + sBb * bz, ldb, (long)bn * 128, k0, lds + 16384);
    __syncthreads();
    short8 af[4][2], bfr[4][2];
#pragma unroll
    for (int i = 0; i < 4; ++i) {
#pragma unroll
      for (int kk = 0; kk < 2; ++kk) {
        int ra = wm * 64 + i * 16 + lr;
        af[i][kk] = *(const short8*)(lds + ((ra * 128 + (kk * 32 + lq * 8) * 2) ^ ((ra & 7) << 4)));
        int rb = wn * 64 + i * 16 + lr;
        bfr[i][kk] = *(const short8*)(lds + 16384 + ((rb * 128 + (kk * 32 + lq * 8) * 2) ^ ((rb & 7) << 4)));
      }
    }
#pragma unroll
    for (int i = 0; i < 4; ++i)
#pragma unroll
      for (int j = 0; j < 4; ++j) {
        acc[i][j] = mfma16(af[i][0], bfr[j][0], acc[i][j]);
        acc[i][j] = mfma16(af[i][1], bfr[j][1], acc[i][j]);
      }
    __syncthreads();
  }
#pragma unroll
  for (int i = 0; i < 4; ++i) {
#pragma unroll
    for (int j = 0; j < 4; ++j) {
#pragma unroll
      for (int r = 0; r < 4; ++r) {
        long row = (long)bm * 128 + wm * 64 + i * 16 + lq * 4 + r;
        long col = (long)bn * 128 + wn * 64 + j * 16 + lr;
        float v = acc[i][j][r];
        if (EPI == 0) {
          v += bias[col];
          ((short*)C + sCb * bz)[row * ldc + col] = f2bf(v);
        } else if (EPI == 1) {
          v += bias[row];
          ((short*)C + sCb * bz)[row * ldc + col] = f2bf(v);
        } else {
          v += bias[col];
          v = fmaxf(v, 0.f);
          ((short*)C + sCb * bz)[row * ldc + col] = f2bf(v);
        }
      }
    }
  }
}

// ---------------- GEMM + fused LayerNorm: C[M,256] = A[M,K] * B[256,K]^T ----------------
// Tile 64 rows x 256 cols (FULL width -> LN per row stays in-block). 4 waves x 16 rows.
// AMODE: 0 = bf16 A via global_load_lds; 2 = combine two NORMALIZED bf16 Opart planes:
//   out_row = w0*on0 + w1*on1, w_c = e^{m_c-M} l_c / sum (exact softmax-split merge).
template <int AMODE, bool WB16>
__global__ void __launch_bounds__(256, 2) gemmln(
    const void* __restrict__ A, const short* __restrict__ Bw,
    const float* __restrict__ bias, const float* __restrict__ resid,
    const float* __restrict__ Mcomb, const float* __restrict__ Lcomb,
    const float* __restrict__ g, const float* __restrict__ be,
    float* __restrict__ outF, short* __restrict__ outB, int K) {
  __shared__ char lds[40960];    // A 8KB @0, B 32KB @8192
  const int tid = threadIdx.x;
  const int bm = blockIdx.x;     // 256 blocks x 64 rows
  const int w = tid >> 6, l = tid & 63;
  const int lr = l & 15, lq = l >> 4;
  char* ldsA = lds;
  char* ldsB = lds + 8192;

  f32x4 acc[16] = {};
  for (int k0 = 0; k0 < K; k0 += 64) {
    // ---- stage A tile [64][64] ----
    if (AMODE == 0) {
      const short* src = (const short*)A;
#pragma unroll
      for (int it = 0; it < 2; ++it) {
        const int span = it * 4096 + w * 1024;
        int idx = (span >> 4) + l;
        int r = idx >> 3, c = idx & 7;
        __builtin_amdgcn_global_load_lds(
            AS1(src + ((long)bm * 64 + r) * K + k0 + ((c ^ (r & 7)) * 8)),
            AS3(ldsA + span), 16, 0, 0);
      }
    } else {
      const short* O0 = (const short*)A;
#pragma unroll
      for (int it = 0; it < 2; ++it) {
        int idx = it * 2048 + tid * 8;
        int r = idx >> 6, c = idx & 63;
        long row = (long)bm * 64 + r;
        float m0 = Mcomb[row], m1 = Mcomb[ROWS + row];
        float l0 = Lcomb[row], l1 = Lcomb[ROWS + row];
        float M = fmaxf(m0, m1);
        float e0 = exp2f(m0 - M) * l0, e1 = exp2f(m1 - M) * l1;
        float inv = 1.f / (e0 + e1);
        float w0 = e0 * inv, w1 = e1 * inv;
        const short* p0 = O0 + row * 256 + k0 + c;
        short8 v0 = *(const short8*)p0;
        short8 v1 = *(const short8*)(p0 + (long)ROWS * 256);
        uint4v u;
#pragma unroll
        for (int j = 0; j < 4; ++j) {
          float x0 = w0 * bf2f(v0[2 * j])     + w1 * bf2f(v1[2 * j]);
          float x1 = w0 * bf2f(v0[2 * j + 1]) + w1 * bf2f(v1[2 * j + 1]);
          u[j] = cvt_pk_bf16(x0, x1);
        }
        *(short8*)(ldsA + ((r * 128 + c * 2) ^ ((r & 7) << 4))) = *(short8*)&u;
      }
    }
    // ---- stage B tile [256][64] ----
#pragma unroll
    for (int it = 0; it < 8; ++it) {
      const int span = it * 4096 + w * 1024;
      int idx = (span >> 4) + l;
      int r = idx >> 3, c = idx & 7;
      __builtin_amdgcn_global_load_lds(
          AS1(Bw + (long)r * K + k0 + ((c ^ (r & 7)) * 8)),
          AS3(ldsB + span), 16, 0, 0);
    }
    __syncthreads();
    short8 af0, af1;
    {
      int ra = w * 16 + lr;
      af0 = *(const short8*)(ldsA + ((ra * 128 + (lq * 8) * 2) ^ ((ra & 7) << 4)));
      af1 = *(const short8*)(ldsA + ((ra * 128 + (32 + lq * 8) * 2) ^ ((ra & 7) << 4)));
    }
#pragma unroll
    for (int j = 0; j < 16; ++j) {
      int rb = j * 16 + lr;
      short8 b0 = *(const short8*)(ldsB + ((rb * 128 + (lq * 8) * 2) ^ ((rb & 7) << 4)));
      short8 b1 = *(const short8*)(ldsB + ((rb * 128 + (32 + lq * 8) * 2) ^ ((rb & 7) << 4)));
      acc[j] = mfma16(af0, b0, acc[j]);
      acc[j] = mfma16(af1, b1, acc[j]);
    }
    __syncthreads();
  }

  // ---- epilogue: bias + resid, LN over each row, write ----
  const long rowbase = (long)bm * 64 + w * 16;
  float bia[16], gg[16], bb[16];
#pragma unroll
  for (int j = 0; j < 16; ++j) {
    int col = j * 16 + lr;
    bia[j] = bias[col]; gg[j] = g[col]; bb[j] = be[col];
  }
#pragma unroll
  for (int r = 0; r < 4; ++r) {
    long row = rowbase + lq * 4 + r;
    float v[16];
    float s = 0.f, s2 = 0.f;
#pragma unroll
    for (int j = 0; j < 16; ++j) {
      float x = acc[j][r] + bia[j] + resid[row * 256 + j * 16 + lr];
      v[j] = x; s += x; s2 += x * x;
    }
#pragma unroll
    for (int mk = 1; mk < 16; mk <<= 1) { s += __shfl_xor(s, mk); s2 += __shfl_xor(s2, mk); }
    float mu = s * (1.f / 256.f);
    float var = s2 * (1.f / 256.f) - mu * mu;
    float rstd = rsqrtf(var + 1e-5f);
#pragma unroll
    for (int j = 0; j < 16; ++j) {
      int col = j * 16 + lr;
      float y = (v[j] - mu) * rstd * gg[j] + bb[j];
      outF[row * 256 + col] = y;
      if (WB16) outB[row * 256 + col] = f2bf(y);
    }
  }
}

// ---------------- flash attention: swapped-QK^T 32x32, permlane pack, dbuf ----------------
// grid 256 (1 block/CU), n&7 = batch = XCD slot (per-XCD KV = 4MB = L2). Block 256 =
// 4 waves, wave owns 32 q rows. LDS: 2 x (K 32KB + V^T 32KB) = 128KB, counted vmcnt(16).
// 1 wave/SIMD (register-locked). Epilogue stores NORMALIZED per-chunk output (o/l_c)
// as bf16 — O(1) magnitudes, same precision as the R1-R11 bf16 Cbuf path (R13 lesson:
// UNnormalized bf16 partials fail; normalized are safe). m_c, l_c kept for exact merge.
__global__ void __launch_bounds__(256, 1) flash_attn(
    const float* __restrict__ Q, const short* __restrict__ Kb,
    const short* __restrict__ Vt, short* __restrict__ Opart,
    float* __restrict__ Mb, float* __restrict__ Lb) {
  __shared__ char lds[131072];
  const int tid = threadIdx.x;
  const int n = blockIdx.x;
  const int b = n & 7;           // XCD-local batch
  const int slot = n >> 3;       // [0,32)
  const int qt = slot & 15;
  const int ch = slot >> 4;      // [0,2)
  const int wid = tid >> 6, l = tid & 63;
  const int ql = l & 31, h = l >> 5;
  const int qrow0 = qt * 128 + wid * 32;
  const float* Qp = Q + ((long)b * LQ + qrow0 + ql) * DQ;
  const short* Kp = Kb + (long)b * LKV * DQ;
  const short* Vp = Vt + (long)b * DQ * LKV;
  const float SCQ = 0.0625f * 1.4426950408889634f;  // folded into Q cast

  auto stage = [&](int bufb, int kv0) {
    char* kqb = lds + bufb * 65536;
    char* vtb = kqb + 32768;
#pragma unroll
    for (int i = 0; i < 8; ++i) {
      const int j = wid * 8192 + i * 1024;       // wave-uniform LDS span base
      {
        int r = (j >> 9) + (l >> 5);
        int cc = l & 31;
        const short* gk = Kp + (long)(kv0 + r) * DQ + ((cc ^ (r & 15)) * 8);
        __builtin_amdgcn_global_load_lds(AS1(gk), AS3(kqb + j), 16, 0, 0);
      }
      {
        int d = (j >> 7) + (l >> 3);
        int cc = l & 7;
        const short* gv = Vp + (long)d * LKV + kv0 + ((cc ^ (d & 7)) * 8);
        __builtin_amdgcn_global_load_lds(AS1(gv), AS3(vtb + j), 16, 0, 0);
      }
    }
  };

  short8 qf[16];
#pragma unroll
  for (int w = 0; w < 16; ++w) {
    const float* p = Qp + w * 16 + h * 8;
    f32x4 f0 = *(const f32x4*)p, f1 = *(const f32x4*)(p + 4);
    short8 v;
#pragma unroll
    for (int j = 0; j < 4; ++j) { v[j] = f2bf(f0[j] * SCQ); v[4 + j] = f2bf(f1[j] * SCQ); }
    qf[w] = v;
  }

  f32x16 o[8] = {};
  float m_r = -1e30f, l_r = 0.f;

  const int kv_lo = ch * (LKV / NCHUNK);
  const int NT = (LKV / NCHUNK) / 64;   // 32 tiles

  stage(0, kv_lo);

  for (int t = 0; t < NT; ++t) {
    if (t + 1 < NT) {
      stage((t + 1) & 1, kv_lo + (t + 1) * 64);
      asm volatile("s_waitcnt vmcnt(16)" ::: "memory");
    } else {
      asm volatile("s_waitcnt vmcnt(0)" ::: "memory");
    }
    __builtin_amdgcn_s_barrier();
    __builtin_amdgcn_sched_barrier(0);
    char* kq = lds + (t & 1) * 65536;
    char* vt = kq + 32768;

    // ---- QK^T both 32-kv subtiles: two independent MFMA chains, interleaved ----
    f32x16 sa = {}, sb = {};
    {
      const int krA = ql, krB = 32 + ql;
      const int baseA = krA * 512, swzA = (krA & 15) << 4;
      const int baseB = krB * 512, swzB = (krB & 15) << 4;
#pragma unroll
      for (int w = 0; w < 16; ++w) {
        short8 kfA = *(const short8*)(kq + ((baseA + w * 32 + h * 16) ^ swzA));
        sa = mfma32(kfA, qf[w], sa);
        short8 kfB = *(const short8*)(kq + ((baseB + w * 32 + h * 16) ^ swzB));
        sb = mfma32(kfB, qf[w], sb);
      }
    }

    // ---- tree-max (depth 5) + shfl_xor cross-half + single deferred rescale ----
    {
      float m8[8];
#pragma unroll
      for (int i = 0; i < 8; ++i)
        m8[i] = fmaxf(fmaxf(sa[i], sa[i + 8]), fmaxf(sb[i], sb[i + 8]));
      float m0 = fmaxf(fmaxf(m8[0], m8[1]), fmaxf(m8[2], m8[3]));
      float m1 = fmaxf(fmaxf(m8[4], m8[5]), fmaxf(m8[6], m8[7]));
      float pmax = fmaxf(m0, m1);
      pmax = fmaxf(pmax, __shfl_xor(pmax, 32));
      if (__any(pmax > m_r + 8.f)) {
        float mn = fmaxf(m_r, pmax);
        float alpha = exp2f(m_r - mn);
        m_r = mn;
        l_r *= alpha;
#pragma unroll
        for (int rr = 0; rr < 16; ++rr) {
          int src = ((rr & 3) + 8 * (rr >> 2) + 4 * h) + 32 * h;
          float ar = __shfl(alpha, src);
#pragma unroll
          for (int nn = 0; nn < 8; ++nn) o[nn][rr] *= ar;
        }
      }
    }

    // ---- exp2 + pack; A-frags via permlane32_swap on DISTINCT registers ----
    short8 paA[2], paB[2];
    float rs0 = 0.f, rs1 = 0.f, rs2 = 0.f, rs3 = 0.f;
    {
      float pA[16];
#pragma unroll
      for (int i = 0; i < 16; ++i) pA[i] = exp2f(sa[i] - m_r);
#pragma unroll
      for (int i = 0; i < 4; ++i) { rs0 += pA[4 * i]; rs1 += pA[4 * i + 1]; rs2 += pA[4 * i + 2]; rs3 += pA[4 * i + 3]; }
#pragma unroll
      for (int v = 0; v < 2; ++v) {
        unsigned w01 = cvt_pk_bf16(pA[8 * v + 0], pA[8 * v + 1]);
        unsigned w23 = cvt_pk_bf16(pA[8 * v + 2], pA[8 * v + 3]);
        unsigned w45 = cvt_pk_bf16(pA[8 * v + 4], pA[8 * v + 5]);
        unsigned w67 = cvt_pk_bf16(pA[8 * v + 6], pA[8 * v + 7]);
        pl32swap(w01, w45);   // w01 -> word0, w45 -> word2
        pl32swap(w23, w67);   // w23 -> word1, w67 -> word3
        uint4v u = {w01, w23, w45, w67};
        paA[v] = *(short8*)&u;
      }
    }
    {
      float pB[16];
#pragma unroll
      for (int i = 0; i < 16; ++i) pB[i] = exp2f(sb[i] - m_r);
#pragma unroll
      for (int i = 0; i < 4; ++i) { rs0 += pB[4 * i]; rs1 += pB[4 * i + 1]; rs2 += pB[4 * i + 2]; rs3 += pB[4 * i + 3]; }
#pragma unroll
      for (int v = 0; v < 2; ++v) {
        unsigned w01 = cvt_pk_bf16(pB[8 * v + 0], pB[8 * v + 1]);
        unsigned w23 = cvt_pk_bf16(pB[8 * v + 2], pB[8 * v + 3]);
        unsigned w45 = cvt_pk_bf16(pB[8 * v + 4], pB[8 * v + 5]);
        unsigned w67 = cvt_pk_bf16(pB[8 * v + 6], pB[8 * v + 7]);
        pl32swap(w01, w45);
        pl32swap(w23, w67);
        uint4v u = {w01, w23, w45, w67};
        paB[v] = *(short8*)&u;
      }
    }
    {
      float rs = (rs0 + rs1) + (rs2 + rs3);
      rs += __shfl_xor(rs, 32);
      l_r += rs;
    }

    // ---- O += P V' for both subtiles: 8 o-chains x 4 mfma (ILP) ----
#pragma unroll
    for (int nn = 0; nn < 8; ++nn) {
      const int d = 32 * nn + ql;
      const int dbase = d * 128, dswz = (d & 7) << 4;
      short8 bv0 = *(const short8*)(vt + ((dbase + 0 * 32 + 16 * h) ^ dswz));
      o[nn] = mfma32(paA[0], bv0, o[nn]);
      short8 bv1 = *(const short8*)(vt + ((dbase + 1 * 32 + 16 * h) ^ dswz));
      o[nn] = mfma32(paA[1], bv1, o[nn]);
      short8 bv2 = *(const short8*)(vt + ((dbase + 2 * 32 + 16 * h) ^ dswz));
      o[nn] = mfma32(paB[0], bv2, o[nn]);
      short8 bv3 = *(const short8*)(vt + ((dbase + 3 * 32 + 16 * h) ^ dswz));
      o[nn] = mfma32(paB[1], bv3, o[nn]);
    }

    asm volatile("s_waitcnt lgkmcnt(0)" ::: "memory");
    __builtin_amdgcn_s_barrier();
    __builtin_amdgcn_sched_barrier(0);
  }

  // epilogue: NORMALIZED partial O (bf16) + per-row m,l. Lane ql owns row ql's
  // (m,l); o[nn][rr] belongs to row f(rr,h) -> fetch 1/l via the same __shfl
  // index pattern as the (validated) alpha broadcast.
  const long rowb = (long)b * LQ + qrow0;
  float inv_l = 1.f / l_r;
#pragma unroll
  for (int rr = 0; rr < 16; ++rr) {
    int rloc = (rr & 3) + 8 * (rr >> 2) + 4 * h;
    float li = __shfl(inv_l, rloc + 32 * h);
    long grow = rowb + rloc;
    short* dst = Opart + ((long)ch * ROWS + grow) * 256 + ql;
#pragma unroll
    for (int nn = 0; nn < 8; ++nn) dst[32 * nn] = f2bf(o[nn][rr] * li);
  }
  if (h == 0) {
    Mb[(long)ch * ROWS + rowb + ql] = m_r;
    Lb[(long)ch * ROWS + rowb + ql] = l_r;
  }
}

// ---------------- launcher ----------------
extern "C" void kernel_launch(void* const* d_in, const int* in_sizes, int n_in,
                              void* d_out, int out_size, void* d_ws, size_t ws_size,
                              hipStream_t stream) {
  const float* query = (const float*)d_in[0];
  const float* key   = (const float*)d_in[1];
  const float* value = (const float*)d_in[2];
  const float* Wk  = (const float*)d_in[3];
  const float* bk  = (const float*)d_in[4];
  const float* Wv  = (const float*)d_in[5];
  const float* bv  = (const float*)d_in[6];
  const float* Wo  = (const float*)d_in[7];
  const float* bo  = (const float*)d_in[8];
  const float* g1  = (const float*)d_in[9];
  const float* b1  = (const float*)d_in[10];
  const float* g2  = (const float*)d_in[11];
  const float* b2  = (const float*)d_in[12];
  const float* W1  = (const float*)d_in[13];
  const float* bf1 = (const float*)d_in[14];
  const float* W2  = (const float*)d_in[15];
  const float* bf2 = (const float*)d_in[16];

  char* ws = (char*)d_ws;
  size_t off = 0;
  auto take = [&](size_t bytes) { char* p = ws + off; off += bytes; return p; };
  short* WkT = (short*)take((size_t)256 * 256 * 2);
  short* WvT = (short*)take((size_t)256 * 256 * 2);
  short* WoT = (short*)take((size_t)256 * 256 * 2);
  short* W1T = (short*)take((size_t)1024 * 256 * 2);
  short* W2T = (short*)take((size_t)256 * 1024 * 2);
  short* Kb  = (short*)take((size_t)NB * LKV * DQ * 2);   // dead after flash -> Hb aliases
  short* Vt  = (short*)take((size_t)NB * DQ * LKV * 2);
  short* Opart = (short*)take((size_t)NCHUNK * ROWS * 256 * 2);   // normalized bf16 partials
  float* Mbuf  = (float*)take((size_t)NCHUNK * ROWS * 4);
  float* Lbuf  = (float*)take((size_t)NCHUNK * ROWS * 4);
  float* Xf    = (float*)take((size_t)ROWS * 256 * 4);
  short* Xb    = (short*)take((size_t)ROWS * 256 * 2);
  short* Hb  = (short*)Kb;               // FF1 out 33.6MB aliases Kb+Vt region (dead)
  (void)ws_size; (void)in_sizes; (void)n_in; (void)out_size;

  dim3 blk(256);
  transpose_all<<<dim3(704), dim3(32, 8), 0, stream>>>(
      Wk, Wv, Wo, W1, W2, WkT, WvT, WoT, W1T, W2T);

  // K' = key @ Wk + bk   -> Kb [B*LKV][256] bf16   (A: f32 reg, B: bf16 gload)
  gemm128<1, 0, 0><<<dim3(2, 256, 1), blk, 0, stream>>>(
      key, 0, 256, WkT, 0, 256, bk, Kb, 0, 256, 256);
  // V'^T = (value @ Wv + bv)^T -> Vt [B][256][LKV] bf16  (A = WvT gload, B = value f32)
  gemm128<0, 1, 1><<<dim3(32, 2, 8), blk, 0, stream>>>(
      WvT, 0, 256, value, (long)LKV * 256, 256, bv, Vt, (long)256 * LKV, LKV, 256);
  // attention (KV-split 2, swapped-QK^T 32x32, permlane pack, dbuf, XCD-pinned)
  flash_attn<<<dim3(256), blk, 0, stream>>>(query, Kb, Vt, Opart, Mbuf, Lbuf);
  // x = LN1(combine(Opart) @ Wo + bo + query) -> Xf f32 + Xb bf16 (combine+LN fused)
  gemmln<2, true><<<dim3(ROWS / 64), blk, 0, stream>>>(
      Opart, WoT, bo, query, Mbuf, Lbuf, g1, b1, Xf, Xb, 256);
  // h = relu(x @ W1 + bf1) -> Hb bf16  (both operands gload)
  gemm128<0, 0, 3><<<dim3(8, 128, 1), blk, 0, stream>>>(
      Xb, 0, 256, W1T, 0, 256, bf1, Hb, 0, 1024, 256);
  // out = LN2(h @ W2 + bf2 + x) -> d_out f32  (LN fused)
  gemmln<0, false><<<dim3(ROWS / 64), blk, 0, stream>>>(
      Hb, W2T, bf2, Xf, nullptr, nullptr, g2, b2, (float*)d_out, nullptr, 1024);
}

// Round 17
// 222.238 us; speedup vs baseline: 1.5863x; 1.0118x over previous
//
#include <hip/hip_runtime.h>
#include <stdint.h>

// ---------------- types / helpers ----------------
typedef __attribute__((ext_vector_type(4))) float f32x4;
typedef __attribute__((ext_vector_type(16))) float f32x16;
typedef __attribute__((ext_vector_type(8))) short short8;
typedef __attribute__((ext_vector_type(4))) short short4v;
typedef __attribute__((ext_vector_type(4))) unsigned uint4v;

__device__ __forceinline__ short f2bf(float f) {
  union { float f; uint32_t u; } v; v.f = f;
  uint32_t r = v.u + 0x7FFFu + ((v.u >> 16) & 1u);
  return (short)(r >> 16);
}

__device__ __forceinline__ float bf2f(short s) {
  union { unsigned u; float f; } v; v.u = ((unsigned)(unsigned short)s) << 16; return v.f;
}

__device__ __forceinline__ unsigned cvt_pk_bf16(float lo, float hi) {
  unsigned r;
  asm("v_cvt_pk_bf16_f32 %0, %1, %2" : "=v"(r) : "v"(lo), "v"(hi));
  return r;
}

// v_permlane32_swap_b32 X, Y: X' = {X.lo, Y.lo}, Y' = {X.hi, Y.hi}.
// ONLY safe when X and Y are guaranteed-distinct registers (distinct producer
// values). R13/R14 lesson: copy-then-swap reductions can alias both "+v"
// operands to ONE VGPR -> in-place swap -> corrupted reductions -> 0.14 FAIL.
// Reductions use __shfl_xor; permlane reserved for the pack path.
__device__ __forceinline__ void pl32swap(unsigned& x, unsigned& y) {
  asm volatile("v_permlane32_swap_b32 %0, %1" : "+v"(x), "+v"(y));
}

__device__ __forceinline__ f32x4 mfma16(short8 a, short8 b, f32x4 c) {
  return __builtin_amdgcn_mfma_f32_16x16x32_bf16(a, b, c, 0, 0, 0);
}
__device__ __forceinline__ f32x16 mfma32(short8 a, short8 b, f32x16 c) {
  return __builtin_amdgcn_mfma_f32_32x32x16_bf16(a, b, c, 0, 0, 0);
}

#define NB 8
#define LQ 2048
#define LKV 4096
#define DQ 256
#define FF 1024
#define NCHUNK 2
#define ROWS (NB * LQ)   // 16384

#define AS1(p) ((const __attribute__((address_space(1))) void*)(p))
#define AS3(p) ((__attribute__((address_space(3))) void*)(p))

// ---------------- all weight transposes in ONE launch ----------------
__global__ void transpose_all(
    const float* __restrict__ Wk, const float* __restrict__ Wv,
    const float* __restrict__ Wo, const float* __restrict__ W1,
    const float* __restrict__ W2,
    short* __restrict__ WkT, short* __restrict__ WvT, short* __restrict__ WoT,
    short* __restrict__ W1T, short* __restrict__ W2T) {
  __shared__ float t[32][33];
  int bid = blockIdx.x;
  const float* in; short* out; int R, C, b0;
  if (bid < 64)       { in = Wk; out = WkT; R = 256;  C = 256;  b0 = bid; }
  else if (bid < 128) { in = Wv; out = WvT; R = 256;  C = 256;  b0 = bid - 64; }
  else if (bid < 192) { in = Wo; out = WoT; R = 256;  C = 256;  b0 = bid - 128; }
  else if (bid < 448) { in = W1; out = W1T; R = 256;  C = 1024; b0 = bid - 192; }
  else                { in = W2; out = W2T; R = 1024; C = 256;  b0 = bid - 448; }
  int nbx = C / 32;
  int c0 = (b0 % nbx) * 32, r0 = (b0 / nbx) * 32;
  int tx = threadIdx.x, ty = threadIdx.y;  // 32 x 8
#pragma unroll
  for (int dy = 0; dy < 32; dy += 8)
    t[ty + dy][tx] = in[(long)(r0 + ty + dy) * C + c0 + tx];
  __syncthreads();
#pragma unroll
  for (int dy = 0; dy < 32; dy += 8)
    out[(long)(c0 + ty + dy) * R + r0 + tx] = f2bf(t[tx][ty + dy]);
}

// ---------------- generic GEMM: C[M,N] = A[M,K] * B[N,K]^T (+epilogues) ----------------
// Tile 128x128, BK=64, 4 waves. AMODE/BMODE: 0 = bf16 via global_load_lds; 1 = f32 reg+cvt_pk.
// EPI: 0 = bf16 + bias[col]; 1 = bf16 + bias[row]; 3 = relu bf16 + bias[col]
template <int AMODE, int BMODE, int EPI>
__global__ void __launch_bounds__(256, 2) gemm128(
    const void* __restrict__ A, long sAb, int lda,
    const void* __restrict__ B, long sBb, int ldb,
    const float* __restrict__ bias,
    void* C, long sCb, int ldc, int K) {
  __shared__ char lds[32768];
  const int tid = threadIdx.x;
  const int bn = blockIdx.x, bm = blockIdx.y, bz = blockIdx.z;
  const int w = tid >> 6, l = tid & 63;
  const int wm = w & 1, wn = w >> 1;
  const int lr = l & 15, lq = l >> 4;

  auto stageReg = [&](const float* src, int ld, long row0, int k0, char* ldsb) {
#pragma unroll
    for (int it = 0; it < 4; ++it) {
      int idx = it * 2048 + tid * 8;
      int r = idx >> 6, c = idx & 63;
      const float* p = src + (row0 + r) * (long)ld + k0 + c;
      f32x4 f0 = *(const f32x4*)p, f1 = *(const f32x4*)(p + 4);
      uint4v u;
      u[0] = cvt_pk_bf16(f0[0], f0[1]); u[1] = cvt_pk_bf16(f0[2], f0[3]);
      u[2] = cvt_pk_bf16(f1[0], f1[1]); u[3] = cvt_pk_bf16(f1[2], f1[3]);
      *(short8*)(ldsb + ((r * 128 + c * 2) ^ ((r & 7) << 4))) = *(short8*)&u;
    }
  };
  auto stageGld = [&](const short* src, int ld, long row0, int k0, char* ldsb) {
#pragma unroll
    for (int it = 0; it < 4; ++it) {
      const int span = it * 4096 + w * 1024;     // wave-uniform
      int idx = (span >> 4) + l;                 // chunk index
      int r = idx >> 3, c = idx & 7;
      __builtin_amdgcn_global_load_lds(
          AS1(src + (row0 + r) * (long)ld + k0 + ((c ^ (r & 7)) * 8)),
          AS3(ldsb + span), 16, 0, 0);
    }
  };

  f32x4 acc[4][4] = {};
  for (int k0 = 0; k0 < K; k0 += 64) {
    if (AMODE == 0)      stageGld((const short*)A + sAb * bz, lda, (long)bm * 128, k0, lds);
    else                 stageReg((const float*)A + sAb * bz, lda, (long)bm * 128, k0, lds);
    if (BMODE == 0)      stageGld((const short*)B + sBb * bz, ldb, (long)bn * 128, k0, lds + 16384);
    else                 stageReg((const float*)B + sBb * bz, ldb, (long)bn * 128, k0, lds + 16384);
    __syncthreads();
    short8 af[4][2], bfr[4][2];
#pragma unroll
    for (int i = 0; i < 4; ++i) {
#pragma unroll
      for (int kk = 0; kk < 2; ++kk) {
        int ra = wm * 64 + i * 16 + lr;
        af[i][kk] = *(const short8*)(lds + ((ra * 128 + (kk * 32 + lq * 8) * 2) ^ ((ra & 7) << 4)));
        int rb = wn * 64 + i * 16 + lr;
        bfr[i][kk] = *(const short8*)(lds + 16384 + ((rb * 128 + (kk * 32 + lq * 8) * 2) ^ ((rb & 7) << 4)));
      }
    }
#pragma unroll
    for (int i = 0; i < 4; ++i)
#pragma unroll
      for (int j = 0; j < 4; ++j) {
        acc[i][j] = mfma16(af[i][0], bfr[j][0], acc[i][j]);
        acc[i][j] = mfma16(af[i][1], bfr[j][1], acc[i][j]);
      }
    __syncthreads();
  }
#pragma unroll
  for (int i = 0; i < 4; ++i) {
#pragma unroll
    for (int j = 0; j < 4; ++j) {
#pragma unroll
      for (int r = 0; r < 4; ++r) {
        long row = (long)bm * 128 + wm * 64 + i * 16 + lq * 4 + r;
        long col = (long)bn * 128 + wn * 64 + j * 16 + lr;
        float v = acc[i][j][r];
        if (EPI == 0) {
          v += bias[col];
          ((short*)C + sCb * bz)[row * ldc + col] = f2bf(v);
        } else if (EPI == 1) {
          v += bias[row];
          ((short*)C + sCb * bz)[row * ldc + col] = f2bf(v);
        } else {
          v += bias[col];
          v = fmaxf(v, 0.f);
          ((short*)C + sCb * bz)[row * ldc + col] = f2bf(v);
        }
      }
    }
  }
}

// ---------------- GEMM + fused LayerNorm: C[M,256] = A[M,K] * B[256,K]^T ----------------
// Tile 64 rows x 256 cols (FULL width -> LN per row stays in-block). 4 waves x 16 rows.
// AMODE: 0 = bf16 A via global_load_lds; 2 = combine two NORMALIZED bf16 Opart planes.
// RESF32: residual dtype (query = f32; LN1-out x = bf16 Xb — R16: saves the Xf f32
// round-trip, ~134MB of HBM; bf16 resid error <=0.004 pre-LN2, well inside threshold).
template <int AMODE, bool RESF32, bool WF32, bool WB16>
__global__ void __launch_bounds__(256, 2) gemmln(
    const void* __restrict__ A, const short* __restrict__ Bw,
    const float* __restrict__ bias, const void* __restrict__ resid,
    const float* __restrict__ Mcomb, const float* __restrict__ Lcomb,
    const float* __restrict__ g, const float* __restrict__ be,
    float* __restrict__ outF, short* __restrict__ outB, int K) {
  __shared__ char lds[40960];    // A 8KB @0, B 32KB @8192
  const int tid = threadIdx.x;
  const int bm = blockIdx.x;     // 256 blocks x 64 rows
  const int w = tid >> 6, l = tid & 63;
  const int lr = l & 15, lq = l >> 4;
  char* ldsA = lds;
  char* ldsB = lds + 8192;

  f32x4 acc[16] = {};
  for (int k0 = 0; k0 < K; k0 += 64) {
    // ---- stage A tile [64][64] ----
    if (AMODE == 0) {
      const short* src = (const short*)A;
#pragma unroll
      for (int it = 0; it < 2; ++it) {
        const int span = it * 4096 + w * 1024;
        int idx = (span >> 4) + l;
        int r = idx >> 3, c = idx & 7;
        __builtin_amdgcn_global_load_lds(
            AS1(src + ((long)bm * 64 + r) * K + k0 + ((c ^ (r & 7)) * 8)),
            AS3(ldsA + span), 16, 0, 0);
      }
    } else {
      const short* O0 = (const short*)A;
#pragma unroll
      for (int it = 0; it < 2; ++it) {
        int idx = it * 2048 + tid * 8;
        int r = idx >> 6, c = idx & 63;
        long row = (long)bm * 64 + r;
        float m0 = Mcomb[row], m1 = Mcomb[ROWS + row];
        float l0 = Lcomb[row], l1 = Lcomb[ROWS + row];
        float M = fmaxf(m0, m1);
        float e0 = exp2f(m0 - M) * l0, e1 = exp2f(m1 - M) * l1;
        float inv = 1.f / (e0 + e1);
        float w0 = e0 * inv, w1 = e1 * inv;
        const short* p0 = O0 + row * 256 + k0 + c;
        short8 v0 = *(const short8*)p0;
        short8 v1 = *(const short8*)(p0 + (long)ROWS * 256);
        uint4v u;
#pragma unroll
        for (int j = 0; j < 4; ++j) {
          float x0 = w0 * bf2f(v0[2 * j])     + w1 * bf2f(v1[2 * j]);
          float x1 = w0 * bf2f(v0[2 * j + 1]) + w1 * bf2f(v1[2 * j + 1]);
          u[j] = cvt_pk_bf16(x0, x1);
        }
        *(short8*)(ldsA + ((r * 128 + c * 2) ^ ((r & 7) << 4))) = *(short8*)&u;
      }
    }
    // ---- stage B tile [256][64] ----
#pragma unroll
    for (int it = 0; it < 8; ++it) {
      const int span = it * 4096 + w * 1024;
      int idx = (span >> 4) + l;
      int r = idx >> 3, c = idx & 7;
      __builtin_amdgcn_global_load_lds(
          AS1(Bw + (long)r * K + k0 + ((c ^ (r & 7)) * 8)),
          AS3(ldsB + span), 16, 0, 0);
    }
    __syncthreads();
    short8 af0, af1;
    {
      int ra = w * 16 + lr;
      af0 = *(const short8*)(ldsA + ((ra * 128 + (lq * 8) * 2) ^ ((ra & 7) << 4)));
      af1 = *(const short8*)(ldsA + ((ra * 128 + (32 + lq * 8) * 2) ^ ((ra & 7) << 4)));
    }
#pragma unroll
    for (int j = 0; j < 16; ++j) {
      int rb = j * 16 + lr;
      short8 b0 = *(const short8*)(ldsB + ((rb * 128 + (lq * 8) * 2) ^ ((rb & 7) << 4)));
      short8 b1 = *(const short8*)(ldsB + ((rb * 128 + (32 + lq * 8) * 2) ^ ((rb & 7) << 4)));
      acc[j] = mfma16(af0, b0, acc[j]);
      acc[j] = mfma16(af1, b1, acc[j]);
    }
    __syncthreads();
  }

  // ---- epilogue: bias + resid, LN over each row, write ----
  const long rowbase = (long)bm * 64 + w * 16;
  float bia[16], gg[16], bb[16];
#pragma unroll
  for (int j = 0; j < 16; ++j) {
    int col = j * 16 + lr;
    bia[j] = bias[col]; gg[j] = g[col]; bb[j] = be[col];
  }
#pragma unroll
  for (int r = 0; r < 4; ++r) {
    long row = rowbase + lq * 4 + r;
    float v[16];
    float s = 0.f, s2 = 0.f;
#pragma unroll
    for (int j = 0; j < 16; ++j) {
      long idx = row * 256 + j * 16 + lr;
      float rx = RESF32 ? ((const float*)resid)[idx] : bf2f(((const short*)resid)[idx]);
      float x = acc[j][r] + bia[j] + rx;
      v[j] = x; s += x; s2 += x * x;
    }
#pragma unroll
    for (int mk = 1; mk < 16; mk <<= 1) { s += __shfl_xor(s, mk); s2 += __shfl_xor(s2, mk); }
    float mu = s * (1.f / 256.f);
    float var = s2 * (1.f / 256.f) - mu * mu;
    float rstd = rsqrtf(var + 1e-5f);
#pragma unroll
    for (int j = 0; j < 16; ++j) {
      int col = j * 16 + lr;
      float y = (v[j] - mu) * rstd * gg[j] + bb[j];
      if (WF32) outF[row * 256 + col] = y;
      if (WB16) outB[row * 256 + col] = f2bf(y);
    }
  }
}

// ---------------- flash attention: swapped-QK^T 32x32, permlane pack, dbuf ----------------
// grid 256 (1 block/CU), n&7 = batch = XCD slot (per-XCD KV = 4MB = L2). Block 256 =
// 4 waves, wave owns 32 q rows. LDS: 2 x (K 32KB + V^T 32KB) = 128KB, counted vmcnt(16).
// 1 wave/SIMD (register-locked). Epilogue stores NORMALIZED per-chunk output (o/l_c)
// as bf16 (O(1) magnitudes — safe; R13: UNnormalized bf16 partials fail).
__global__ void __launch_bounds__(256, 1) flash_attn(
    const float* __restrict__ Q, const short* __restrict__ Kb,
    const short* __restrict__ Vt, short* __restrict__ Opart,
    float* __restrict__ Mb, float* __restrict__ Lb) {
  __shared__ char lds[131072];
  const int tid = threadIdx.x;
  const int n = blockIdx.x;
  const int b = n & 7;           // XCD-local batch
  const int slot = n >> 3;       // [0,32)
  const int qt = slot & 15;
  const int ch = slot >> 4;      // [0,2)
  const int wid = tid >> 6, l = tid & 63;
  const int ql = l & 31, h = l >> 5;
  const int qrow0 = qt * 128 + wid * 32;
  const float* Qp = Q + ((long)b * LQ + qrow0 + ql) * DQ;
  const short* Kp = Kb + (long)b * LKV * DQ;
  const short* Vp = Vt + (long)b * DQ * LKV;
  const float SCQ = 0.0625f * 1.4426950408889634f;  // folded into Q cast

  auto stage = [&](int bufb, int kv0) {
    char* kqb = lds + bufb * 65536;
    char* vtb = kqb + 32768;
#pragma unroll
    for (int i = 0; i < 8; ++i) {
      const int j = wid * 8192 + i * 1024;       // wave-uniform LDS span base
      {
        int r = (j >> 9) + (l >> 5);
        int cc = l & 31;
        const short* gk = Kp + (long)(kv0 + r) * DQ + ((cc ^ (r & 15)) * 8);
        __builtin_amdgcn_global_load_lds(AS1(gk), AS3(kqb + j), 16, 0, 0);
      }
      {
        int d = (j >> 7) + (l >> 3);
        int cc = l & 7;
        const short* gv = Vp + (long)d * LKV + kv0 + ((cc ^ (d & 7)) * 8);
        __builtin_amdgcn_global_load_lds(AS1(gv), AS3(vtb + j), 16, 0, 0);
      }
    }
  };

  short8 qf[16];
#pragma unroll
  for (int w = 0; w < 16; ++w) {
    const float* p = Qp + w * 16 + h * 8;
    f32x4 f0 = *(const f32x4*)p, f1 = *(const f32x4*)(p + 4);
    short8 v;
#pragma unroll
    for (int j = 0; j < 4; ++j) { v[j] = f2bf(f0[j] * SCQ); v[4 + j] = f2bf(f1[j] * SCQ); }
    qf[w] = v;
  }

  f32x16 o[8] = {};
  float m_r = -1e30f, l_r = 0.f;

  const int kv_lo = ch * (LKV / NCHUNK);
  const int NT = (LKV / NCHUNK) / 64;   // 32 tiles

  stage(0, kv_lo);

  for (int t = 0; t < NT; ++t) {
    if (t + 1 < NT) {
      stage((t + 1) & 1, kv_lo + (t + 1) * 64);
      asm volatile("s_waitcnt vmcnt(16)" ::: "memory");
    } else {
      asm volatile("s_waitcnt vmcnt(0)" ::: "memory");
    }
    __builtin_amdgcn_s_barrier();
    __builtin_amdgcn_sched_barrier(0);
    char* kq = lds + (t & 1) * 65536;
    char* vt = kq + 32768;

    // ---- QK^T both 32-kv subtiles: two independent MFMA chains, interleaved ----
    f32x16 sa = {}, sb = {};
    {
      const int krA = ql, krB = 32 + ql;
      const int baseA = krA * 512, swzA = (krA & 15) << 4;
      const int baseB = krB * 512, swzB = (krB & 15) << 4;
#pragma unroll
      for (int w = 0; w < 16; ++w) {
        short8 kfA = *(const short8*)(kq + ((baseA + w * 32 + h * 16) ^ swzA));
        sa = mfma32(kfA, qf[w], sa);
        short8 kfB = *(const short8*)(kq + ((baseB + w * 32 + h * 16) ^ swzB));
        sb = mfma32(kfB, qf[w], sb);
      }
    }

    // ---- tree-max (depth 5) + shfl_xor cross-half + single deferred rescale ----
    {
      float m8[8];
#pragma unroll
      for (int i = 0; i < 8; ++i)
        m8[i] = fmaxf(fmaxf(sa[i], sa[i + 8]), fmaxf(sb[i], sb[i + 8]));
      float m0 = fmaxf(fmaxf(m8[0], m8[1]), fmaxf(m8[2], m8[3]));
      float m1 = fmaxf(fmaxf(m8[4], m8[5]), fmaxf(m8[6], m8[7]));
      float pmax = fmaxf(m0, m1);
      pmax = fmaxf(pmax, __shfl_xor(pmax, 32));
      if (__any(pmax > m_r + 8.f)) {
        float mn = fmaxf(m_r, pmax);
        float alpha = exp2f(m_r - mn);
        m_r = mn;
        l_r *= alpha;
#pragma unroll
        for (int rr = 0; rr < 16; ++rr) {
          int src = ((rr & 3) + 8 * (rr >> 2) + 4 * h) + 32 * h;
          float ar = __shfl(alpha, src);
#pragma unroll
          for (int nn = 0; nn < 8; ++nn) o[nn][rr] *= ar;
        }
      }
    }

    // ---- exp2 + pack; A-frags via permlane32_swap on DISTINCT registers ----
    short8 paA[2], paB[2];
    float rs0 = 0.f, rs1 = 0.f, rs2 = 0.f, rs3 = 0.f;
    {
      float pA[16];
#pragma unroll
      for (int i = 0; i < 16; ++i) pA[i] = exp2f(sa[i] - m_r);
#pragma unroll
      for (int i = 0; i < 4; ++i) { rs0 += pA[4 * i]; rs1 += pA[4 * i + 1]; rs2 += pA[4 * i + 2]; rs3 += pA[4 * i + 3]; }
#pragma unroll
      for (int v = 0; v < 2; ++v) {
        unsigned w01 = cvt_pk_bf16(pA[8 * v + 0], pA[8 * v + 1]);
        unsigned w23 = cvt_pk_bf16(pA[8 * v + 2], pA[8 * v + 3]);
        unsigned w45 = cvt_pk_bf16(pA[8 * v + 4], pA[8 * v + 5]);
        unsigned w67 = cvt_pk_bf16(pA[8 * v + 6], pA[8 * v + 7]);
        pl32swap(w01, w45);   // w01 -> word0, w45 -> word2
        pl32swap(w23, w67);   // w23 -> word1, w67 -> word3
        uint4v u = {w01, w23, w45, w67};
        paA[v] = *(short8*)&u;
      }
    }
    {
      float pB[16];
#pragma unroll
      for (int i = 0; i < 16; ++i) pB[i] = exp2f(sb[i] - m_r);
#pragma unroll
      for (int i = 0; i < 4; ++i) { rs0 += pB[4 * i]; rs1 += pB[4 * i + 1]; rs2 += pB[4 * i + 2]; rs3 += pB[4 * i + 3]; }
#pragma unroll
      for (int v = 0; v < 2; ++v) {
        unsigned w01 = cvt_pk_bf16(pB[8 * v + 0], pB[8 * v + 1]);
        unsigned w23 = cvt_pk_bf16(pB[8 * v + 2], pB[8 * v + 3]);
        unsigned w45 = cvt_pk_bf16(pB[8 * v + 4], pB[8 * v + 5]);
        unsigned w67 = cvt_pk_bf16(pB[8 * v + 6], pB[8 * v + 7]);
        pl32swap(w01, w45);
        pl32swap(w23, w67);
        uint4v u = {w01, w23, w45, w67};
        paB[v] = *(short8*)&u;
      }
    }
    {
      float rs = (rs0 + rs1) + (rs2 + rs3);
      rs += __shfl_xor(rs, 32);
      l_r += rs;
    }

    // ---- O += P V' for both subtiles: 8 o-chains x 4 mfma (ILP) ----
#pragma unroll
    for (int nn = 0; nn < 8; ++nn) {
      const int d = 32 * nn + ql;
      const int dbase = d * 128, dswz = (d & 7) << 4;
      short8 bv0 = *(const short8*)(vt + ((dbase + 0 * 32 + 16 * h) ^ dswz));
      o[nn] = mfma32(paA[0], bv0, o[nn]);
      short8 bv1 = *(const short8*)(vt + ((dbase + 1 * 32 + 16 * h) ^ dswz));
      o[nn] = mfma32(paA[1], bv1, o[nn]);
      short8 bv2 = *(const short8*)(vt + ((dbase + 2 * 32 + 16 * h) ^ dswz));
      o[nn] = mfma32(paB[0], bv2, o[nn]);
      short8 bv3 = *(const short8*)(vt + ((dbase + 3 * 32 + 16 * h) ^ dswz));
      o[nn] = mfma32(paB[1], bv3, o[nn]);
    }

    asm volatile("s_waitcnt lgkmcnt(0)" ::: "memory");
    __builtin_amdgcn_s_barrier();
    __builtin_amdgcn_sched_barrier(0);
  }

  // epilogue: NORMALIZED partial O (bf16) + per-row m,l.
  const long rowb = (long)b * LQ + qrow0;
  float inv_l = 1.f / l_r;
#pragma unroll
  for (int rr = 0; rr < 16; ++rr) {
    int rloc = (rr & 3) + 8 * (rr >> 2) + 4 * h;
    float li = __shfl(inv_l, rloc + 32 * h);
    long grow = rowb + rloc;
    short* dst = Opart + ((long)ch * ROWS + grow) * 256 + ql;
#pragma unroll
    for (int nn = 0; nn < 8; ++nn) dst[32 * nn] = f2bf(o[nn][rr] * li);
  }
  if (h == 0) {
    Mb[(long)ch * ROWS + rowb + ql] = m_r;
    Lb[(long)ch * ROWS + rowb + ql] = l_r;
  }
}

// ---------------- launcher ----------------
extern "C" void kernel_launch(void* const* d_in, const int* in_sizes, int n_in,
                              void* d_out, int out_size, void* d_ws, size_t ws_size,
                              hipStream_t stream) {
  const float* query = (const float*)d_in[0];
  const float* key   = (const float*)d_in[1];
  const float* value = (const float*)d_in[2];
  const float* Wk  = (const float*)d_in[3];
  const float* bk  = (const float*)d_in[4];
  const float* Wv  = (const float*)d_in[5];
  const float* bv  = (const float*)d_in[6];
  const float* Wo  = (const float*)d_in[7];
  const float* bo  = (const float*)d_in[8];
  const float* g1  = (const float*)d_in[9];
  const float* b1  = (const float*)d_in[10];
  const float* g2  = (const float*)d_in[11];
  const float* b2  = (const float*)d_in[12];
  const float* W1  = (const float*)d_in[13];
  const float* bf1 = (const float*)d_in[14];
  const float* W2  = (const float*)d_in[15];
  const float* bf2 = (const float*)d_in[16];

  char* ws = (char*)d_ws;
  size_t off = 0;
  auto take = [&](size_t bytes) { char* p = ws + off; off += bytes; return p; };
  short* WkT = (short*)take((size_t)256 * 256 * 2);
  short* WvT = (short*)take((size_t)256 * 256 * 2);
  short* WoT = (short*)take((size_t)256 * 256 * 2);
  short* W1T = (short*)take((size_t)1024 * 256 * 2);
  short* W2T = (short*)take((size_t)256 * 1024 * 2);
  short* Kb  = (short*)take((size_t)NB * LKV * DQ * 2);   // dead after flash -> Hb aliases
  short* Vt  = (short*)take((size_t)NB * DQ * LKV * 2);
  short* Opart = (short*)take((size_t)NCHUNK * ROWS * 256 * 2);   // normalized bf16 partials
  float* Mbuf  = (float*)take((size_t)NCHUNK * ROWS * 4);
  float* Lbuf  = (float*)take((size_t)NCHUNK * ROWS * 4);
  short* Xb    = (short*)take((size_t)ROWS * 256 * 2);    // LN1 out bf16 (FF1 input + FF2 resid)
  short* Hb  = (short*)Kb;               // FF1 out 33.6MB aliases Kb+Vt region (dead)
  (void)ws_size; (void)in_sizes; (void)n_in; (void)out_size;

  dim3 blk(256);
  transpose_all<<<dim3(704), dim3(32, 8), 0, stream>>>(
      Wk, Wv, Wo, W1, W2, WkT, WvT, WoT, W1T, W2T);

  // K' = key @ Wk + bk   -> Kb [B*LKV][256] bf16   (A: f32 reg, B: bf16 gload)
  gemm128<1, 0, 0><<<dim3(2, 256, 1), blk, 0, stream>>>(
      key, 0, 256, WkT, 0, 256, bk, Kb, 0, 256, 256);
  // V'^T = (value @ Wv + bv)^T -> Vt [B][256][LKV] bf16  (A = WvT gload, B = value f32)
  gemm128<0, 1, 1><<<dim3(32, 2, 8), blk, 0, stream>>>(
      WvT, 0, 256, value, (long)LKV * 256, 256, bv, Vt, (long)256 * LKV, LKV, 256);
  // attention (KV-split 2, swapped-QK^T 32x32, permlane pack, dbuf, XCD-pinned)
  flash_attn<<<dim3(256), blk, 0, stream>>>(query, Kb, Vt, Opart, Mbuf, Lbuf);
  // x = LN1(combine(Opart) @ Wo + bo + query) -> Xb bf16 ONLY (no f32 round-trip)
  gemmln<2, true, false, true><<<dim3(ROWS / 64), blk, 0, stream>>>(
      Opart, WoT, bo, query, Mbuf, Lbuf, g1, b1, nullptr, Xb, 256);
  // h = relu(x @ W1 + bf1) -> Hb bf16  (both operands gload)
  gemm128<0, 0, 3><<<dim3(8, 128, 1), blk, 0, stream>>>(
      Xb, 0, 256, W1T, 0, 256, bf1, Hb, 0, 1024, 256);
  // out = LN2(h @ W2 + bf2 + x) -> d_out f32  (resid = Xb bf16)
  gemmln<0, false, true, false><<<dim3(ROWS / 64), blk, 0, stream>>>(
      Hb, W2T, bf2, Xb, nullptr, nullptr, g2, b2, (float*)d_out, nullptr, 1024);
}

// Round 18
// 214.042 us; speedup vs baseline: 1.6471x; 1.0383x over previous
//
#include <hip/hip_runtime.h>
#include <stdint.h>

// ---------------- types / helpers ----------------
typedef __attribute__((ext_vector_type(4))) float f32x4;
typedef __attribute__((ext_vector_type(16))) float f32x16;
typedef __attribute__((ext_vector_type(8))) short short8;
typedef __attribute__((ext_vector_type(4))) short short4v;
typedef __attribute__((ext_vector_type(4))) unsigned uint4v;

__device__ __forceinline__ short f2bf(float f) {
  union { float f; uint32_t u; } v; v.f = f;
  uint32_t r = v.u + 0x7FFFu + ((v.u >> 16) & 1u);
  return (short)(r >> 16);
}

__device__ __forceinline__ float bf2f(short s) {
  union { unsigned u; float f; } v; v.u = ((unsigned)(unsigned short)s) << 16; return v.f;
}

__device__ __forceinline__ unsigned cvt_pk_bf16(float lo, float hi) {
  unsigned r;
  asm("v_cvt_pk_bf16_f32 %0, %1, %2" : "=v"(r) : "v"(lo), "v"(hi));
  return r;
}

// v_permlane32_swap_b32 X, Y: X' = {X.lo, Y.lo}, Y' = {X.hi, Y.hi}.
// ONLY safe when X and Y are guaranteed-distinct registers. Reductions use
// __shfl_xor (R13/R14 lesson: copy-then-swap can alias "+v" operands).
__device__ __forceinline__ void pl32swap(unsigned& x, unsigned& y) {
  asm volatile("v_permlane32_swap_b32 %0, %1" : "+v"(x), "+v"(y));
}

__device__ __forceinline__ f32x4 mfma16(short8 a, short8 b, f32x4 c) {
  return __builtin_amdgcn_mfma_f32_16x16x32_bf16(a, b, c, 0, 0, 0);
}
__device__ __forceinline__ f32x16 mfma32(short8 a, short8 b, f32x16 c) {
  return __builtin_amdgcn_mfma_f32_32x32x16_bf16(a, b, c, 0, 0, 0);
}

#define NB 8
#define LQ 2048
#define LKV 4096
#define DQ 256
#define FF 1024
#define NCHUNK 2
#define ROWS (NB * LQ)   // 16384

#define AS1(p) ((const __attribute__((address_space(1))) void*)(p))
#define AS3(p) ((__attribute__((address_space(3))) void*)(p))

// ---------------- all weight transposes in ONE launch ----------------
__global__ void transpose_all(
    const float* __restrict__ Wk, const float* __restrict__ Wv,
    const float* __restrict__ Wo, const float* __restrict__ W1,
    const float* __restrict__ W2,
    short* __restrict__ WkT, short* __restrict__ WvT, short* __restrict__ WoT,
    short* __restrict__ W1T, short* __restrict__ W2T) {
  __shared__ float t[32][33];
  int bid = blockIdx.x;
  const float* in; short* out; int R, C, b0;
  if (bid < 64)       { in = Wk; out = WkT; R = 256;  C = 256;  b0 = bid; }
  else if (bid < 128) { in = Wv; out = WvT; R = 256;  C = 256;  b0 = bid - 64; }
  else if (bid < 192) { in = Wo; out = WoT; R = 256;  C = 256;  b0 = bid - 128; }
  else if (bid < 448) { in = W1; out = W1T; R = 256;  C = 1024; b0 = bid - 192; }
  else                { in = W2; out = W2T; R = 1024; C = 256;  b0 = bid - 448; }
  int nbx = C / 32;
  int c0 = (b0 % nbx) * 32, r0 = (b0 / nbx) * 32;
  int tx = threadIdx.x, ty = threadIdx.y;  // 32 x 8
#pragma unroll
  for (int dy = 0; dy < 32; dy += 8)
    t[ty + dy][tx] = in[(long)(r0 + ty + dy) * C + c0 + tx];
  __syncthreads();
#pragma unroll
  for (int dy = 0; dy < 32; dy += 8)
    out[(long)(c0 + ty + dy) * R + r0 + tx] = f2bf(t[tx][ty + dy]);
}

// ---------------- generic GEMM: C[M,N] = A[M,K] * B[N,K]^T (+epilogues) ----------------
// Tile 128x128, BK=64, 4 waves. AMODE/BMODE: 0 = bf16 via global_load_lds; 1 = f32 reg+cvt_pk.
// EPI: 0 = bf16 + bias[col]; 1 = bf16 + bias[row]; 3 = relu bf16 + bias[col]
template <int AMODE, int BMODE, int EPI>
__global__ void __launch_bounds__(256, 2) gemm128(
    const void* __restrict__ A, long sAb, int lda,
    const void* __restrict__ B, long sBb, int ldb,
    const float* __restrict__ bias,
    void* C, long sCb, int ldc, int K) {
  __shared__ char lds[32768];
  const int tid = threadIdx.x;
  const int bn = blockIdx.x, bm = blockIdx.y, bz = blockIdx.z;
  const int w = tid >> 6, l = tid & 63;
  const int wm = w & 1, wn = w >> 1;
  const int lr = l & 15, lq = l >> 4;

  auto stageReg = [&](const float* src, int ld, long row0, int k0, char* ldsb) {
#pragma unroll
    for (int it = 0; it < 4; ++it) {
      int idx = it * 2048 + tid * 8;
      int r = idx >> 6, c = idx & 63;
      const float* p = src + (row0 + r) * (long)ld + k0 + c;
      f32x4 f0 = *(const f32x4*)p, f1 = *(const f32x4*)(p + 4);
      uint4v u;
      u[0] = cvt_pk_bf16(f0[0], f0[1]); u[1] = cvt_pk_bf16(f0[2], f0[3]);
      u[2] = cvt_pk_bf16(f1[0], f1[1]); u[3] = cvt_pk_bf16(f1[2], f1[3]);
      *(short8*)(ldsb + ((r * 128 + c * 2) ^ ((r & 7) << 4))) = *(short8*)&u;
    }
  };
  auto stageGld = [&](const short* src, int ld, long row0, int k0, char* ldsb) {
#pragma unroll
    for (int it = 0; it < 4; ++it) {
      const int span = it * 4096 + w * 1024;     // wave-uniform
      int idx = (span >> 4) + l;                 // chunk index
      int r = idx >> 3, c = idx & 7;
      __builtin_amdgcn_global_load_lds(
          AS1(src + (row0 + r) * (long)ld + k0 + ((c ^ (r & 7)) * 8)),
          AS3(ldsb + span), 16, 0, 0);
    }
  };

  f32x4 acc[4][4] = {};
  for (int k0 = 0; k0 < K; k0 += 64) {
    if (AMODE == 0)      stageGld((const short*)A + sAb * bz, lda, (long)bm * 128, k0, lds);
    else                 stageReg((const float*)A + sAb * bz, lda, (long)bm * 128, k0, lds);
    if (BMODE == 0)      stageGld((const short*)B + sBb * bz, ldb, (long)bn * 128, k0, lds + 16384);
    else                 stageReg((const float*)B + sBb * bz, ldb, (long)bn * 128, k0, lds + 16384);
    __syncthreads();
    short8 af[4][2], bfr[4][2];
#pragma unroll
    for (int i = 0; i < 4; ++i) {
#pragma unroll
      for (int kk = 0; kk < 2; ++kk) {
        int ra = wm * 64 + i * 16 + lr;
        af[i][kk] = *(const short8*)(lds + ((ra * 128 + (kk * 32 + lq * 8) * 2) ^ ((ra & 7) << 4)));
        int rb = wn * 64 + i * 16 + lr;
        bfr[i][kk] = *(const short8*)(lds + 16384 + ((rb * 128 + (kk * 32 + lq * 8) * 2) ^ ((rb & 7) << 4)));
      }
    }
#pragma unroll
    for (int i = 0; i < 4; ++i)
#pragma unroll
      for (int j = 0; j < 4; ++j) {
        acc[i][j] = mfma16(af[i][0], bfr[j][0], acc[i][j]);
        acc[i][j] = mfma16(af[i][1], bfr[j][1], acc[i][j]);
      }
    __syncthreads();
  }
#pragma unroll
  for (int i = 0; i < 4; ++i) {
#pragma unroll
    for (int j = 0; j < 4; ++j) {
#pragma unroll
      for (int r = 0; r < 4; ++r) {
        long row = (long)bm * 128 + wm * 64 + i * 16 + lq * 4 + r;
        long col = (long)bn * 128 + wn * 64 + j * 16 + lr;
        float v = acc[i][j][r];
        if (EPI == 0) {
          v += bias[col];
          ((short*)C + sCb * bz)[row * ldc + col] = f2bf(v);
        } else if (EPI == 1) {
          v += bias[row];
          ((short*)C + sCb * bz)[row * ldc + col] = f2bf(v);
        } else {
          v += bias[col];
          v = fmaxf(v, 0.f);
          ((short*)C + sCb * bz)[row * ldc + col] = f2bf(v);
        }
      }
    }
  }
}

// ---------------- GEMM + fused LayerNorm: C[M,256] = A[M,K] * B[256,K]^T ----------------
// Tile 64 rows x 256 cols (FULL width -> LN per row stays in-block). 4 waves x 16 rows.
// AMODE 0 (FF2): both operands gload_lds, DOUBLE-BUFFERED with counted vmcnt(10)
//   (flash-proven T3/T4; 10 = per-thread loads/stage: A 2 + B 8). LDS 80KB.
// AMODE 2 (Wo): combine two NORMALIZED bf16 Opart planes; single-buffer (mixed
//   reg-load+ds_write accounting — kept simple per R13/14 lessons).
// RESF32: residual dtype (query f32 / Xb bf16).
template <int AMODE, bool RESF32, bool WF32, bool WB16>
__global__ void __launch_bounds__(256, 2) gemmln(
    const void* __restrict__ A, const short* __restrict__ Bw,
    const float* __restrict__ bias, const void* __restrict__ resid,
    const float* __restrict__ Mcomb, const float* __restrict__ Lcomb,
    const float* __restrict__ g, const float* __restrict__ be,
    float* __restrict__ outF, short* __restrict__ outB, int K) {
  __shared__ char lds[(AMODE == 0) ? 81920 : 40960];   // buf: A 8KB + B 32KB (x2 if dbuf)
  const int tid = threadIdx.x;
  const int bm = blockIdx.x;     // 256 blocks x 64 rows
  const int w = tid >> 6, l = tid & 63;
  const int lr = l & 15, lq = l >> 4;

  // stage A [64][64] bf16 via gload (AMODE 0)
  auto stageA0 = [&](int k0, char* ldsA) {
    const short* src = (const short*)A;
#pragma unroll
    for (int it = 0; it < 2; ++it) {
      const int span = it * 4096 + w * 1024;
      int idx = (span >> 4) + l;
      int r = idx >> 3, c = idx & 7;
      __builtin_amdgcn_global_load_lds(
          AS1(src + ((long)bm * 64 + r) * K + k0 + ((c ^ (r & 7)) * 8)),
          AS3(ldsA + span), 16, 0, 0);
    }
  };
  // stage B [256][64] bf16 via gload
  auto stageB = [&](int k0, char* ldsB) {
#pragma unroll
    for (int it = 0; it < 8; ++it) {
      const int span = it * 4096 + w * 1024;
      int idx = (span >> 4) + l;
      int r = idx >> 3, c = idx & 7;
      __builtin_amdgcn_global_load_lds(
          AS1(Bw + (long)r * K + k0 + ((c ^ (r & 7)) * 8)),
          AS3(ldsB + span), 16, 0, 0);
    }
  };
  // combine-stage A (AMODE 2): softmax-split merge of normalized partials
  auto stageA2 = [&](int k0, char* ldsA) {
    const short* O0 = (const short*)A;
#pragma unroll
    for (int it = 0; it < 2; ++it) {
      int idx = it * 2048 + tid * 8;
      int r = idx >> 6, c = idx & 63;
      long row = (long)bm * 64 + r;
      float m0 = Mcomb[row], m1 = Mcomb[ROWS + row];
      float l0 = Lcomb[row], l1 = Lcomb[ROWS + row];
      float M = fmaxf(m0, m1);
      float e0 = exp2f(m0 - M) * l0, e1 = exp2f(m1 - M) * l1;
      float inv = 1.f / (e0 + e1);
      float w0 = e0 * inv, w1 = e1 * inv;
      const short* p0 = O0 + row * 256 + k0 + c;
      short8 v0 = *(const short8*)p0;
      short8 v1 = *(const short8*)(p0 + (long)ROWS * 256);
      uint4v u;
#pragma unroll
      for (int j = 0; j < 4; ++j) {
        float x0 = w0 * bf2f(v0[2 * j])     + w1 * bf2f(v1[2 * j]);
        float x1 = w0 * bf2f(v0[2 * j + 1]) + w1 * bf2f(v1[2 * j + 1]);
        u[j] = cvt_pk_bf16(x0, x1);
      }
      *(short8*)(ldsA + ((r * 128 + c * 2) ^ ((r & 7) << 4))) = *(short8*)&u;
    }
  };

  auto compute = [&](char* ldsA, char* ldsB, f32x4* acc) {
    short8 af0, af1;
    int ra = w * 16 + lr;
    af0 = *(const short8*)(ldsA + ((ra * 128 + (lq * 8) * 2) ^ ((ra & 7) << 4)));
    af1 = *(const short8*)(ldsA + ((ra * 128 + (32 + lq * 8) * 2) ^ ((ra & 7) << 4)));
#pragma unroll
    for (int j = 0; j < 16; ++j) {
      int rb = j * 16 + lr;
      short8 b0 = *(const short8*)(ldsB + ((rb * 128 + (lq * 8) * 2) ^ ((rb & 7) << 4)));
      short8 b1 = *(const short8*)(ldsB + ((rb * 128 + (32 + lq * 8) * 2) ^ ((rb & 7) << 4)));
      acc[j] = mfma16(af0, b0, acc[j]);
      acc[j] = mfma16(af1, b1, acc[j]);
    }
  };

  f32x4 acc[16] = {};
  if (AMODE == 0) {
    // double-buffered pipeline, counted vmcnt (10 loads/thread/stage in flight)
    const int NS = K / 64;
    stageA0(0, lds);
    stageB(0, lds + 8192);
    for (int ks = 0; ks < NS; ++ks) {
      if (ks + 1 < NS) {
        char* nbuf = lds + ((ks + 1) & 1) * 40960;
        stageA0((ks + 1) * 64, nbuf);
        stageB((ks + 1) * 64, nbuf + 8192);
        asm volatile("s_waitcnt vmcnt(10)" ::: "memory");  // stage ks landed
      } else {
        asm volatile("s_waitcnt vmcnt(0)" ::: "memory");
      }
      __builtin_amdgcn_s_barrier();
      __builtin_amdgcn_sched_barrier(0);
      char* buf = lds + (ks & 1) * 40960;
      compute(buf, buf + 8192, acc);
      asm volatile("s_waitcnt lgkmcnt(0)" ::: "memory");
      __builtin_amdgcn_s_barrier();
      __builtin_amdgcn_sched_barrier(0);
    }
  } else {
    for (int k0 = 0; k0 < K; k0 += 64) {
      stageA2(k0, lds);
      stageB(k0, lds + 8192);
      __syncthreads();
      compute(lds, lds + 8192, acc);
      __syncthreads();
    }
  }

  // ---- epilogue: bias + resid, LN over each row, write ----
  const long rowbase = (long)bm * 64 + w * 16;
  float bia[16], gg[16], bb[16];
#pragma unroll
  for (int j = 0; j < 16; ++j) {
    int col = j * 16 + lr;
    bia[j] = bias[col]; gg[j] = g[col]; bb[j] = be[col];
  }
#pragma unroll
  for (int r = 0; r < 4; ++r) {
    long row = rowbase + lq * 4 + r;
    float v[16];
    float s = 0.f, s2 = 0.f;
#pragma unroll
    for (int j = 0; j < 16; ++j) {
      long idx = row * 256 + j * 16 + lr;
      float rx = RESF32 ? ((const float*)resid)[idx] : bf2f(((const short*)resid)[idx]);
      float x = acc[j][r] + bia[j] + rx;
      v[j] = x; s += x; s2 += x * x;
    }
#pragma unroll
    for (int mk = 1; mk < 16; mk <<= 1) { s += __shfl_xor(s, mk); s2 += __shfl_xor(s2, mk); }
    float mu = s * (1.f / 256.f);
    float var = s2 * (1.f / 256.f) - mu * mu;
    float rstd = rsqrtf(var + 1e-5f);
#pragma unroll
    for (int j = 0; j < 16; ++j) {
      int col = j * 16 + lr;
      float y = (v[j] - mu) * rstd * gg[j] + bb[j];
      if (WF32) outF[row * 256 + col] = y;
      if (WB16) outB[row * 256 + col] = f2bf(y);
    }
  }
}

// ---------------- flash attention: swapped-QK^T 32x32, permlane pack, dbuf ----------------
// grid 256 (1 block/CU), n&7 = batch = XCD slot (per-XCD KV = 4MB = L2). Block 256 =
// 4 waves, wave owns 32 q rows. LDS: 2 x (K 32KB + V^T 32KB) = 128KB, counted vmcnt(16).
// 1 wave/SIMD (register-locked). Epilogue stores NORMALIZED per-chunk output (o/l_c)
// as bf16 (O(1) magnitudes — safe; R13: UNnormalized bf16 partials fail).
__global__ void __launch_bounds__(256, 1) flash_attn(
    const float* __restrict__ Q, const short* __restrict__ Kb,
    const short* __restrict__ Vt, short* __restrict__ Opart,
    float* __restrict__ Mb, float* __restrict__ Lb) {
  __shared__ char lds[131072];
  const int tid = threadIdx.x;
  const int n = blockIdx.x;
  const int b = n & 7;           // XCD-local batch
  const int slot = n >> 3;       // [0,32)
  const int qt = slot & 15;
  const int ch = slot >> 4;      // [0,2)
  const int wid = tid >> 6, l = tid & 63;
  const int ql = l & 31, h = l >> 5;
  const int qrow0 = qt * 128 + wid * 32;
  const float* Qp = Q + ((long)b * LQ + qrow0 + ql) * DQ;
  const short* Kp = Kb + (long)b * LKV * DQ;
  const short* Vp = Vt + (long)b * DQ * LKV;
  const float SCQ = 0.0625f * 1.4426950408889634f;  // folded into Q cast

  auto stage = [&](int bufb, int kv0) {
    char* kqb = lds + bufb * 65536;
    char* vtb = kqb + 32768;
#pragma unroll
    for (int i = 0; i < 8; ++i) {
      const int j = wid * 8192 + i * 1024;       // wave-uniform LDS span base
      {
        int r = (j >> 9) + (l >> 5);
        int cc = l & 31;
        const short* gk = Kp + (long)(kv0 + r) * DQ + ((cc ^ (r & 15)) * 8);
        __builtin_amdgcn_global_load_lds(AS1(gk), AS3(kqb + j), 16, 0, 0);
      }
      {
        int d = (j >> 7) + (l >> 3);
        int cc = l & 7;
        const short* gv = Vp + (long)d * LKV + kv0 + ((cc ^ (d & 7)) * 8);
        __builtin_amdgcn_global_load_lds(AS1(gv), AS3(vtb + j), 16, 0, 0);
      }
    }
  };

  short8 qf[16];
#pragma unroll
  for (int w = 0; w < 16; ++w) {
    const float* p = Qp + w * 16 + h * 8;
    f32x4 f0 = *(const f32x4*)p, f1 = *(const f32x4*)(p + 4);
    short8 v;
#pragma unroll
    for (int j = 0; j < 4; ++j) { v[j] = f2bf(f0[j] * SCQ); v[4 + j] = f2bf(f1[j] * SCQ); }
    qf[w] = v;
  }

  f32x16 o[8] = {};
  float m_r = -1e30f, l_r = 0.f;

  const int kv_lo = ch * (LKV / NCHUNK);
  const int NT = (LKV / NCHUNK) / 64;   // 32 tiles

  stage(0, kv_lo);

  for (int t = 0; t < NT; ++t) {
    if (t + 1 < NT) {
      stage((t + 1) & 1, kv_lo + (t + 1) * 64);
      asm volatile("s_waitcnt vmcnt(16)" ::: "memory");
    } else {
      asm volatile("s_waitcnt vmcnt(0)" ::: "memory");
    }
    __builtin_amdgcn_s_barrier();
    __builtin_amdgcn_sched_barrier(0);
    char* kq = lds + (t & 1) * 65536;
    char* vt = kq + 32768;

    // ---- QK^T both 32-kv subtiles: two independent MFMA chains, interleaved ----
    f32x16 sa = {}, sb = {};
    {
      const int krA = ql, krB = 32 + ql;
      const int baseA = krA * 512, swzA = (krA & 15) << 4;
      const int baseB = krB * 512, swzB = (krB & 15) << 4;
#pragma unroll
      for (int w = 0; w < 16; ++w) {
        short8 kfA = *(const short8*)(kq + ((baseA + w * 32 + h * 16) ^ swzA));
        sa = mfma32(kfA, qf[w], sa);
        short8 kfB = *(const short8*)(kq + ((baseB + w * 32 + h * 16) ^ swzB));
        sb = mfma32(kfB, qf[w], sb);
      }
    }

    // ---- tree-max (depth 5) + shfl_xor cross-half + single deferred rescale ----
    {
      float m8[8];
#pragma unroll
      for (int i = 0; i < 8; ++i)
        m8[i] = fmaxf(fmaxf(sa[i], sa[i + 8]), fmaxf(sb[i], sb[i + 8]));
      float m0 = fmaxf(fmaxf(m8[0], m8[1]), fmaxf(m8[2], m8[3]));
      float m1 = fmaxf(fmaxf(m8[4], m8[5]), fmaxf(m8[6], m8[7]));
      float pmax = fmaxf(m0, m1);
      pmax = fmaxf(pmax, __shfl_xor(pmax, 32));
      if (__any(pmax > m_r + 8.f)) {
        float mn = fmaxf(m_r, pmax);
        float alpha = exp2f(m_r - mn);
        m_r = mn;
        l_r *= alpha;
#pragma unroll
        for (int rr = 0; rr < 16; ++rr) {
          int src = ((rr & 3) + 8 * (rr >> 2) + 4 * h) + 32 * h;
          float ar = __shfl(alpha, src);
#pragma unroll
          for (int nn = 0; nn < 8; ++nn) o[nn][rr] *= ar;
        }
      }
    }

    // ---- exp2 + pack; A-frags via permlane32_swap on DISTINCT registers ----
    short8 paA[2], paB[2];
    float rs0 = 0.f, rs1 = 0.f, rs2 = 0.f, rs3 = 0.f;
    {
      float pA[16];
#pragma unroll
      for (int i = 0; i < 16; ++i) pA[i] = exp2f(sa[i] - m_r);
#pragma unroll
      for (int i = 0; i < 4; ++i) { rs0 += pA[4 * i]; rs1 += pA[4 * i + 1]; rs2 += pA[4 * i + 2]; rs3 += pA[4 * i + 3]; }
#pragma unroll
      for (int v = 0; v < 2; ++v) {
        unsigned w01 = cvt_pk_bf16(pA[8 * v + 0], pA[8 * v + 1]);
        unsigned w23 = cvt_pk_bf16(pA[8 * v + 2], pA[8 * v + 3]);
        unsigned w45 = cvt_pk_bf16(pA[8 * v + 4], pA[8 * v + 5]);
        unsigned w67 = cvt_pk_bf16(pA[8 * v + 6], pA[8 * v + 7]);
        pl32swap(w01, w45);   // w01 -> word0, w45 -> word2
        pl32swap(w23, w67);   // w23 -> word1, w67 -> word3
        uint4v u = {w01, w23, w45, w67};
        paA[v] = *(short8*)&u;
      }
    }
    {
      float pB[16];
#pragma unroll
      for (int i = 0; i < 16; ++i) pB[i] = exp2f(sb[i] - m_r);
#pragma unroll
      for (int i = 0; i < 4; ++i) { rs0 += pB[4 * i]; rs1 += pB[4 * i + 1]; rs2 += pB[4 * i + 2]; rs3 += pB[4 * i + 3]; }
#pragma unroll
      for (int v = 0; v < 2; ++v) {
        unsigned w01 = cvt_pk_bf16(pB[8 * v + 0], pB[8 * v + 1]);
        unsigned w23 = cvt_pk_bf16(pB[8 * v + 2], pB[8 * v + 3]);
        unsigned w45 = cvt_pk_bf16(pB[8 * v + 4], pB[8 * v + 5]);
        unsigned w67 = cvt_pk_bf16(pB[8 * v + 6], pB[8 * v + 7]);
        pl32swap(w01, w45);
        pl32swap(w23, w67);
        uint4v u = {w01, w23, w45, w67};
        paB[v] = *(short8*)&u;
      }
    }
    {
      float rs = (rs0 + rs1) + (rs2 + rs3);
      rs += __shfl_xor(rs, 32);
      l_r += rs;
    }

    // ---- O += P V' for both subtiles: 8 o-chains x 4 mfma (ILP) ----
#pragma unroll
    for (int nn = 0; nn < 8; ++nn) {
      const int d = 32 * nn + ql;
      const int dbase = d * 128, dswz = (d & 7) << 4;
      short8 bv0 = *(const short8*)(vt + ((dbase + 0 * 32 + 16 * h) ^ dswz));
      o[nn] = mfma32(paA[0], bv0, o[nn]);
      short8 bv1 = *(const short8*)(vt + ((dbase + 1 * 32 + 16 * h) ^ dswz));
      o[nn] = mfma32(paA[1], bv1, o[nn]);
      short8 bv2 = *(const short8*)(vt + ((dbase + 2 * 32 + 16 * h) ^ dswz));
      o[nn] = mfma32(paB[0], bv2, o[nn]);
      short8 bv3 = *(const short8*)(vt + ((dbase + 3 * 32 + 16 * h) ^ dswz));
      o[nn] = mfma32(paB[1], bv3, o[nn]);
    }

    asm volatile("s_waitcnt lgkmcnt(0)" ::: "memory");
    __builtin_amdgcn_s_barrier();
    __builtin_amdgcn_sched_barrier(0);
  }

  // epilogue: NORMALIZED partial O (bf16) + per-row m,l.
  const long rowb = (long)b * LQ + qrow0;
  float inv_l = 1.f / l_r;
#pragma unroll
  for (int rr = 0; rr < 16; ++rr) {
    int rloc = (rr & 3) + 8 * (rr >> 2) + 4 * h;
    float li = __shfl(inv_l, rloc + 32 * h);
    long grow = rowb + rloc;
    short* dst = Opart + ((long)ch * ROWS + grow) * 256 + ql;
#pragma unroll
    for (int nn = 0; nn < 8; ++nn) dst[32 * nn] = f2bf(o[nn][rr] * li);
  }
  if (h == 0) {
    Mb[(long)ch * ROWS + rowb + ql] = m_r;
    Lb[(long)ch * ROWS + rowb + ql] = l_r;
  }
}

// ---------------- launcher ----------------
extern "C" void kernel_launch(void* const* d_in, const int* in_sizes, int n_in,
                              void* d_out, int out_size, void* d_ws, size_t ws_size,
                              hipStream_t stream) {
  const float* query = (const float*)d_in[0];
  const float* key   = (const float*)d_in[1];
  const float* value = (const float*)d_in[2];
  const float* Wk  = (const float*)d_in[3];
  const float* bk  = (const float*)d_in[4];
  const float* Wv  = (const float*)d_in[5];
  const float* bv  = (const float*)d_in[6];
  const float* Wo  = (const float*)d_in[7];
  const float* bo  = (const float*)d_in[8];
  const float* g1  = (const float*)d_in[9];
  const float* b1  = (const float*)d_in[10];
  const float* g2  = (const float*)d_in[11];
  const float* b2  = (const float*)d_in[12];
  const float* W1  = (const float*)d_in[13];
  const float* bf1 = (const float*)d_in[14];
  const float* W2  = (const float*)d_in[15];
  const float* bf2 = (const float*)d_in[16];

  char* ws = (char*)d_ws;
  size_t off = 0;
  auto take = [&](size_t bytes) { char* p = ws + off; off += bytes; return p; };
  short* WkT = (short*)take((size_t)256 * 256 * 2);
  short* WvT = (short*)take((size_t)256 * 256 * 2);
  short* WoT = (short*)take((size_t)256 * 256 * 2);
  short* W1T = (short*)take((size_t)1024 * 256 * 2);
  short* W2T = (short*)take((size_t)256 * 1024 * 2);
  short* Kb  = (short*)take((size_t)NB * LKV * DQ * 2);   // dead after flash -> Hb aliases
  short* Vt  = (short*)take((size_t)NB * DQ * LKV * 2);
  short* Opart = (short*)take((size_t)NCHUNK * ROWS * 256 * 2);   // normalized bf16 partials
  float* Mbuf  = (float*)take((size_t)NCHUNK * ROWS * 4);
  float* Lbuf  = (float*)take((size_t)NCHUNK * ROWS * 4);
  short* Xb    = (short*)take((size_t)ROWS * 256 * 2);    // LN1 out bf16 (FF1 input + FF2 resid)
  short* Hb  = (short*)Kb;               // FF1 out 33.6MB aliases Kb+Vt region (dead)
  (void)ws_size; (void)in_sizes; (void)n_in; (void)out_size;

  dim3 blk(256);
  transpose_all<<<dim3(704), dim3(32, 8), 0, stream>>>(
      Wk, Wv, Wo, W1, W2, WkT, WvT, WoT, W1T, W2T);

  // K' = key @ Wk + bk   -> Kb [B*LKV][256] bf16   (A: f32 reg, B: bf16 gload)
  gemm128<1, 0, 0><<<dim3(2, 256, 1), blk, 0, stream>>>(
      key, 0, 256, WkT, 0, 256, bk, Kb, 0, 256, 256);
  // V'^T = (value @ Wv + bv)^T -> Vt [B][256][LKV] bf16  (A = WvT gload, B = value f32)
  gemm128<0, 1, 1><<<dim3(32, 2, 8), blk, 0, stream>>>(
      WvT, 0, 256, value, (long)LKV * 256, 256, bv, Vt, (long)256 * LKV, LKV, 256);
  // attention (KV-split 2, swapped-QK^T 32x32, permlane pack, dbuf, XCD-pinned)
  flash_attn<<<dim3(256), blk, 0, stream>>>(query, Kb, Vt, Opart, Mbuf, Lbuf);
  // x = LN1(combine(Opart) @ Wo + bo + query) -> Xb bf16 ONLY
  gemmln<2, true, false, true><<<dim3(ROWS / 64), blk, 0, stream>>>(
      Opart, WoT, bo, query, Mbuf, Lbuf, g1, b1, nullptr, Xb, 256);
  // h = relu(x @ W1 + bf1) -> Hb bf16  (both operands gload)
  gemm128<0, 0, 3><<<dim3(8, 128, 1), blk, 0, stream>>>(
      Xb, 0, 256, W1T, 0, 256, bf1, Hb, 0, 1024, 256);
  // out = LN2(h @ W2 + bf2 + x) -> d_out f32  (resid = Xb bf16; dbuf pipeline)
  gemmln<0, false, true, false><<<dim3(ROWS / 64), blk, 0, stream>>>(
      Hb, W2T, bf2, Xb, nullptr, nullptr, g2, b2, (float*)d_out, nullptr, 1024);
}